// Round 14
// baseline (216.791 us; speedup 1.0000x reference)
//
#include <hip/hip_runtime.h>
#include <hip/hip_fp16.h>

#define LEAKY 0.2f
#define BSH 7
#define BN 128      // nodes per bucket = 1<<BSH
#define CHUNK 4096  // edges per partition workgroup
#define NBMAX 1024  // max buckets supported by LDS arrays

__device__ __forceinline__ float leaky(float l) {
  return l >= 0.f ? l : LEAKY * l;
}

typedef _Float16 f16x2 __attribute__((ext_vector_type(2)));

__device__ __forceinline__ float fdot2(unsigned a, unsigned b, float c) {
#if __has_builtin(__builtin_amdgcn_fdot2)
  return __builtin_amdgcn_fdot2(__builtin_bit_cast(f16x2, a),
                                __builtin_bit_cast(f16x2, b), c, false);
#else
  __half2 ha = *(__half2*)&a, hb = *(__half2*)&b;
  float2 fa = __half22float2(ha), fb = __half22float2(hb);
  return fmaf(fa.x, fb.x, fmaf(fa.y, fb.y, c));
#endif
}

__device__ __forceinline__ int packsplat(float w) {
  const __half2 s = __half2half2(__float2half(w));
  return *(const int*)&s;
}
__device__ __forceinline__ __half2 asH2(unsigned u) { return *(__half2*)&u; }

// ---------------- Tiled GEMM: single-stage LDS (whole K), one barrier ----------------
// x-tile + W staged fully (<=35 KB), then an unbroken K-length dot2 stretch.
template<int K, int CO, int H, bool IN_F32>
__global__ __launch_bounds__(256)
void gat_gemm4(const void* __restrict__ xin, const float* __restrict__ W,
               const float* __restrict__ atts, const float* __restrict__ attd,
               __half* __restrict__ hh, float* __restrict__ sa, float* __restrict__ da,
               int N) {
  constexpr int CG = CO / 4;          // 16 or 8
  constexpr int BM = (256 / CG) * 4;  // 64 or 128
  constexpr int C = CO / H;
  constexpr int LDW = K / 2 + 4;      // uints per row (16B-aligned, benign banks)

  __shared__ unsigned xs[BM][LDW];
  __shared__ unsigned ws[CO][LDW];

  const int t = (int)threadIdx.x;
  const int cg = t % CG;
  const int ng = t / CG;
  const int n0 = (int)blockIdx.x * BM;

  // ---- stage ALL of x-tile ----
  if constexpr (IN_F32) {
    const float* x = (const float*)xin;
    constexpr int F4R = K / 4;
    constexpr int TOT = BM * F4R;
    for (int f = t; f < TOT; f += 256) {
      const int r = f / F4R, c4 = f % F4R;
      int row = n0 + r; row = row < N ? row : N - 1;
      const float4 v = *(const float4*)(x + (size_t)row * K + c4 * 4);
      const __half2 h0 = __floats2half2_rn(v.x, v.y);
      const __half2 h1 = __floats2half2_rn(v.z, v.w);
      xs[r][c4 * 2]     = *(const unsigned*)&h0;
      xs[r][c4 * 2 + 1] = *(const unsigned*)&h1;
    }
  } else {
    const __half* x = (const __half*)xin;
    constexpr int U4R = K / 8;
    constexpr int TOT = BM * U4R;
    for (int f = t; f < TOT; f += 256) {
      const int r = f / U4R, c = f % U4R;
      int row = n0 + r; row = row < N ? row : N - 1;
      const uint4 v = *(const uint4*)(x + (size_t)row * K + c * 8);
      *(uint4*)&xs[r][c * 4] = v;
    }
  }
  // ---- stage ALL of W ----
  {
    constexpr int F4R = K / 4;
    constexpr int TOT = CO * F4R;
    for (int f = t; f < TOT; f += 256) {
      const int r = f / F4R, c4 = f % F4R;
      const float4 v = *(const float4*)(W + (size_t)r * K + c4 * 4);
      const __half2 h0 = __floats2half2_rn(v.x, v.y);
      const __half2 h1 = __floats2half2_rn(v.z, v.w);
      ws[r][c4 * 2]     = *(const unsigned*)&h0;
      ws[r][c4 * 2 + 1] = *(const unsigned*)&h1;
    }
  }
  __syncthreads();

  float acc[4][4] = {};
  #pragma unroll
  for (int k = 0; k < K; k += 8) {
    uint4 xa[4], wb[4];
    #pragma unroll
    for (int i = 0; i < 4; ++i) xa[i] = *(const uint4*)&xs[ng * 4 + i][k / 2];
    #pragma unroll
    for (int j = 0; j < 4; ++j) wb[j] = *(const uint4*)&ws[cg + CG * j][k / 2];
    #pragma unroll
    for (int i = 0; i < 4; ++i) {
      #pragma unroll
      for (int j = 0; j < 4; ++j) {
        acc[i][j] = fdot2(xa[i].x, wb[j].x, acc[i][j]);
        acc[i][j] = fdot2(xa[i].y, wb[j].y, acc[i][j]);
        acc[i][j] = fdot2(xa[i].z, wb[j].z, acc[i][j]);
        acc[i][j] = fdot2(xa[i].w, wb[j].w, acc[i][j]);
      }
    }
  }

  // ---- fused sa/da + stores ----
  float as_[4], ad_[4];
  #pragma unroll
  for (int j = 0; j < 4; ++j) {
    as_[j] = atts[cg + CG * j];
    ad_[j] = attd[cg + CG * j];
  }
  float ps[4][H] = {}, pd[4][H] = {};
  #pragma unroll
  for (int i = 0; i < 4; ++i) {
    #pragma unroll
    for (int j = 0; j < 4; ++j) {
      const int hd = (CG * j) / C;
      ps[i][hd] = fmaf(acc[i][j], as_[j], ps[i][hd]);
      pd[i][hd] = fmaf(acc[i][j], ad_[j], pd[i][hd]);
    }
  }
  #pragma unroll
  for (int m = 1; m < CG; m <<= 1) {
    #pragma unroll
    for (int i = 0; i < 4; ++i) {
      #pragma unroll
      for (int hd = 0; hd < H; ++hd) {
        ps[i][hd] += __shfl_xor(ps[i][hd], m, 64);
        pd[i][hd] += __shfl_xor(pd[i][hd], m, 64);
      }
    }
  }

  #pragma unroll
  for (int i = 0; i < 4; ++i) {
    const int n = n0 + ng * 4 + i;
    if (n < N) {
      #pragma unroll
      for (int j = 0; j < 4; ++j)
        hh[(size_t)n * CO + cg + CG * j] = __float2half(acc[i][j]);
      if (cg == 0) {
        #pragma unroll
        for (int hd = 0; hd < H; ++hd) {
          sa[n * H + hd] = ps[i][hd];
          da[n * H + hd] = pd[i][hd];
        }
      }
    }
  }
}

// ---------------- Edge aggregation, H=2 (64 ch): 8 nodes/wave, 16B/lane ----------------
__global__ __launch_bounds__(256)
void gat_edge2(const __half* __restrict__ hh,
               const float* __restrict__ sa, const float* __restrict__ da,
               const int* __restrict__ rowp, const int* __restrict__ col,
               const float* __restrict__ bias, const float* __restrict__ gamma,
               const float* __restrict__ beta, __half* __restrict__ out, int N) {
  __shared__ int2 wst[4][8][9][2];    // [wave][oct][edge(8)+pad][head]
  const int t = (int)threadIdx.x;
  const int lane = t & 63;
  const int wib = t >> 6;
  const int oct = lane >> 3;
  const int l = lane & 7;             // channels 8l .. 8l+7
  const int headq = l >> 2;
  const int wgl = (int)((blockIdx.x * blockDim.x + t) >> 6);
  const int n = wgl * 8 + oct;
  const bool valid = (n < N);
  const int nc = valid ? n : N - 1;
  const int beg = rowp[nc];
  const int end = rowp[nc + 1];
  const float2 dvv = *(const float2*)(da + (size_t)nc * 2);
  const __half* __restrict__ hp = hh;

  const __half2 z = __float2half2_rn(0.f);
  __half2 A0 = z, A1 = z, A2 = z, A3 = z;
  __half2 B0 = z, B1 = z, B2 = z, B3 = z;
  __half2 qA = z, qB = z;

  int sP = 0; float2 pP = make_float2(0.f, 0.f);
  if (beg < end) {
    const int c0 = min(8, end - beg);
    if (l < c0) { sP = col[beg + l]; pP = *(const float2*)(sa + (size_t)sP * 2); }
  }

  for (int b0 = beg; b0 < end; b0 += 8) {
    const int cnt = min(8, end - b0);
    if (l < cnt) {
      int2 e0; e0.x = sP; e0.y = packsplat(__expf(leaky(pP.x + dvv.x)));
      int2 e1; e1.x = sP; e1.y = packsplat(__expf(leaky(pP.y + dvv.y)));
      wst[wib][oct][l][0] = e0;
      wst[wib][oct][l][1] = e1;
    }
    const int nb0 = b0 + 8;
    if (nb0 < end) {
      const int ncnt = min(8, end - nb0);
      if (l < ncnt) { sP = col[nb0 + l]; pP = *(const float2*)(sa + (size_t)sP * 2); }
    }
    int i = 0;
    for (; i + 4 <= cnt; i += 4) {
      const int2 e0 = wst[wib][oct][i][headq];
      const int2 e1 = wst[wib][oct][i + 1][headq];
      const int2 e2 = wst[wib][oct][i + 2][headq];
      const int2 e3 = wst[wib][oct][i + 3][headq];
      const uint4 h0 = *(const uint4*)(hp + ((size_t)e0.x << 6) + 8 * l);
      const uint4 h1 = *(const uint4*)(hp + ((size_t)e1.x << 6) + 8 * l);
      const uint4 h2 = *(const uint4*)(hp + ((size_t)e2.x << 6) + 8 * l);
      const uint4 h3 = *(const uint4*)(hp + ((size_t)e3.x << 6) + 8 * l);
      const __half2 w0 = asH2(e0.y), w1 = asH2(e1.y), w2 = asH2(e2.y), w3 = asH2(e3.y);
      qA = __hadd2(qA, __hadd2(w0, w1));
      qB = __hadd2(qB, __hadd2(w2, w3));
      A0 = __hfma2(w0, asH2(h0.x), A0); A1 = __hfma2(w0, asH2(h0.y), A1);
      A2 = __hfma2(w0, asH2(h0.z), A2); A3 = __hfma2(w0, asH2(h0.w), A3);
      B0 = __hfma2(w1, asH2(h1.x), B0); B1 = __hfma2(w1, asH2(h1.y), B1);
      B2 = __hfma2(w1, asH2(h1.z), B2); B3 = __hfma2(w1, asH2(h1.w), B3);
      A0 = __hfma2(w2, asH2(h2.x), A0); A1 = __hfma2(w2, asH2(h2.y), A1);
      A2 = __hfma2(w2, asH2(h2.z), A2); A3 = __hfma2(w2, asH2(h2.w), A3);
      B0 = __hfma2(w3, asH2(h3.x), B0); B1 = __hfma2(w3, asH2(h3.y), B1);
      B2 = __hfma2(w3, asH2(h3.z), B2); B3 = __hfma2(w3, asH2(h3.w), B3);
    }
    for (; i < cnt; ++i) {
      const int2 e = wst[wib][oct][i][headq];
      const uint4 hv = *(const uint4*)(hp + ((size_t)e.x << 6) + 8 * l);
      const __half2 w = asH2(e.y);
      qA = __hadd2(qA, w);
      A0 = __hfma2(w, asH2(hv.x), A0); A1 = __hfma2(w, asH2(hv.y), A1);
      A2 = __hfma2(w, asH2(hv.z), A2); A3 = __hfma2(w, asH2(hv.w), A3);
    }
  }

  const float c0 = __low2float(A0) + __low2float(B0);
  const float c1 = __high2float(A0) + __high2float(B0);
  const float c2 = __low2float(A1) + __low2float(B1);
  const float c3 = __high2float(A1) + __high2float(B1);
  const float c4 = __low2float(A2) + __low2float(B2);
  const float c5 = __high2float(A2) + __high2float(B2);
  const float c6 = __low2float(A3) + __low2float(B3);
  const float c7 = __high2float(A3) + __high2float(B3);
  const float qf = __low2float(qA) + __low2float(qB);

  const float inv = 1.f / fmaxf(qf, 1e-16f);
  const uint4 hr = *(const uint4*)(hp + ((size_t)nc << 6) + 8 * l);
  const float2 r0 = __half22float2(asH2(hr.x));
  const float2 r1 = __half22float2(asH2(hr.y));
  const float2 r2 = __half22float2(asH2(hr.z));
  const float2 r3 = __half22float2(asH2(hr.w));
  const float4 bi0 = *(const float4*)(bias + 8 * l);
  const float4 bi1 = *(const float4*)(bias + 8 * l + 4);
  float v0 = c0 * inv + r0.x + bi0.x;
  float v1 = c1 * inv + r0.y + bi0.y;
  float v2 = c2 * inv + r1.x + bi0.z;
  float v3 = c3 * inv + r1.y + bi0.w;
  float v4 = c4 * inv + r2.x + bi1.x;
  float v5 = c5 * inv + r2.y + bi1.y;
  float v6 = c6 * inv + r3.x + bi1.z;
  float v7 = c7 * inv + r3.y + bi1.w;
  {
    float s = ((v0 + v1) + (v2 + v3)) + ((v4 + v5) + (v6 + v7));
    s += __shfl_xor(s, 1, 64); s += __shfl_xor(s, 2, 64); s += __shfl_xor(s, 4, 64);
    const float mu = s * (1.f / 64.f);
    const float d0 = v0 - mu, d1 = v1 - mu, d2 = v2 - mu, d3 = v3 - mu;
    const float d4 = v4 - mu, d5 = v5 - mu, d6 = v6 - mu, d7 = v7 - mu;
    float vs = ((d0 * d0 + d1 * d1) + (d2 * d2 + d3 * d3)) +
               ((d4 * d4 + d5 * d5) + (d6 * d6 + d7 * d7));
    vs += __shfl_xor(vs, 1, 64); vs += __shfl_xor(vs, 2, 64); vs += __shfl_xor(vs, 4, 64);
    const float rs = rsqrtf(vs * (1.f / 64.f) + 1e-5f);
    const float4 g0 = *(const float4*)(gamma + 8 * l);
    const float4 g1 = *(const float4*)(gamma + 8 * l + 4);
    const float4 e0 = *(const float4*)(beta + 8 * l);
    const float4 e1 = *(const float4*)(beta + 8 * l + 4);
    v0 = fmaxf(d0 * rs * g0.x + e0.x, 0.f);
    v1 = fmaxf(d1 * rs * g0.y + e0.y, 0.f);
    v2 = fmaxf(d2 * rs * g0.z + e0.z, 0.f);
    v3 = fmaxf(d3 * rs * g0.w + e0.w, 0.f);
    v4 = fmaxf(d4 * rs * g1.x + e1.x, 0.f);
    v5 = fmaxf(d5 * rs * g1.y + e1.y, 0.f);
    v6 = fmaxf(d6 * rs * g1.z + e1.z, 0.f);
    v7 = fmaxf(d7 * rs * g1.w + e1.w, 0.f);
  }
  if (valid) {
    const __half2 o0 = __floats2half2_rn(v0, v1);
    const __half2 o1 = __floats2half2_rn(v2, v3);
    const __half2 o2 = __floats2half2_rn(v4, v5);
    const __half2 o3 = __floats2half2_rn(v6, v7);
    uint4 o;
    o.x = *(const unsigned*)&o0; o.y = *(const unsigned*)&o1;
    o.z = *(const unsigned*)&o2; o.w = *(const unsigned*)&o3;
    *(uint4*)(out + (size_t)n * 64 + 8 * l) = o;
  }
}

// ---------------- Edge aggregation, H=1 (32 ch): 16 nodes/wave, 16B/lane ----------------
__global__ __launch_bounds__(256)
void gat_edge1(const __half* __restrict__ hh,
               const float* __restrict__ sa, const float* __restrict__ da,
               const int* __restrict__ rowp, const int* __restrict__ col,
               const float* __restrict__ bias, float* __restrict__ out, int N) {
  __shared__ int2 wst[4][16][5];      // [wave][node(16)][edge(4)+pad]
  const int t = (int)threadIdx.x;
  const int lane = t & 63;
  const int wib = t >> 6;
  const int nq = lane >> 2;           // node within wave
  const int l = lane & 3;             // channels 8l .. 8l+7
  const int wgl = (int)((blockIdx.x * blockDim.x + t) >> 6);
  const int n = wgl * 16 + nq;
  const bool valid = (n < N);
  const int nc = valid ? n : N - 1;
  const int beg = rowp[nc];
  const int end = rowp[nc + 1];
  const float dv = da[nc];
  const __half* __restrict__ hp = hh;

  const __half2 z = __float2half2_rn(0.f);
  __half2 A0 = z, A1 = z, A2 = z, A3 = z;
  __half2 B0 = z, B1 = z, B2 = z, B3 = z;
  __half2 qA = z, qB = z;

  int sP = 0; float pP = 0.f;
  if (beg < end) {
    const int c0 = min(4, end - beg);
    if (l < c0) { sP = col[beg + l]; pP = sa[sP]; }
  }

  for (int b0 = beg; b0 < end; b0 += 4) {
    const int cnt = min(4, end - b0);
    if (l < cnt) {
      int2 e; e.x = sP; e.y = packsplat(__expf(leaky(pP + dv)));
      wst[wib][nq][l] = e;
    }
    const int nb0 = b0 + 4;
    if (nb0 < end) {
      const int ncnt = min(4, end - nb0);
      if (l < ncnt) { sP = col[nb0 + l]; pP = sa[sP]; }
    }
    if (cnt == 4) {
      const int2 e0 = wst[wib][nq][0];
      const int2 e1 = wst[wib][nq][1];
      const int2 e2 = wst[wib][nq][2];
      const int2 e3 = wst[wib][nq][3];
      const uint4 h0 = *(const uint4*)(hp + ((size_t)e0.x << 5) + 8 * l);
      const uint4 h1 = *(const uint4*)(hp + ((size_t)e1.x << 5) + 8 * l);
      const uint4 h2 = *(const uint4*)(hp + ((size_t)e2.x << 5) + 8 * l);
      const uint4 h3 = *(const uint4*)(hp + ((size_t)e3.x << 5) + 8 * l);
      const __half2 w0 = asH2(e0.y), w1 = asH2(e1.y), w2 = asH2(e2.y), w3 = asH2(e3.y);
      qA = __hadd2(qA, __hadd2(w0, w1));
      qB = __hadd2(qB, __hadd2(w2, w3));
      A0 = __hfma2(w0, asH2(h0.x), A0); A1 = __hfma2(w0, asH2(h0.y), A1);
      A2 = __hfma2(w0, asH2(h0.z), A2); A3 = __hfma2(w0, asH2(h0.w), A3);
      B0 = __hfma2(w1, asH2(h1.x), B0); B1 = __hfma2(w1, asH2(h1.y), B1);
      B2 = __hfma2(w1, asH2(h1.z), B2); B3 = __hfma2(w1, asH2(h1.w), B3);
      A0 = __hfma2(w2, asH2(h2.x), A0); A1 = __hfma2(w2, asH2(h2.y), A1);
      A2 = __hfma2(w2, asH2(h2.z), A2); A3 = __hfma2(w2, asH2(h2.w), A3);
      B0 = __hfma2(w3, asH2(h3.x), B0); B1 = __hfma2(w3, asH2(h3.y), B1);
      B2 = __hfma2(w3, asH2(h3.z), B2); B3 = __hfma2(w3, asH2(h3.w), B3);
    } else {
      for (int i = 0; i < cnt; ++i) {
        const int2 e = wst[wib][nq][i];
        const uint4 hv = *(const uint4*)(hp + ((size_t)e.x << 5) + 8 * l);
        const __half2 w = asH2(e.y);
        qA = __hadd2(qA, w);
        A0 = __hfma2(w, asH2(hv.x), A0); A1 = __hfma2(w, asH2(hv.y), A1);
        A2 = __hfma2(w, asH2(hv.z), A2); A3 = __hfma2(w, asH2(hv.w), A3);
      }
    }
  }

  if (valid) {
    const float c0 = __low2float(A0) + __low2float(B0);
    const float c1 = __high2float(A0) + __high2float(B0);
    const float c2 = __low2float(A1) + __low2float(B1);
    const float c3 = __high2float(A1) + __high2float(B1);
    const float c4 = __low2float(A2) + __low2float(B2);
    const float c5 = __high2float(A2) + __high2float(B2);
    const float c6 = __low2float(A3) + __low2float(B3);
    const float c7 = __high2float(A3) + __high2float(B3);
    const float qf = __low2float(qA) + __low2float(qB);
    const float inv = 1.f / fmaxf(qf, 1e-16f);
    const uint4 hr = *(const uint4*)(hp + ((size_t)nc << 5) + 8 * l);
    const float2 r0 = __half22float2(asH2(hr.x));
    const float2 r1 = __half22float2(asH2(hr.y));
    const float2 r2 = __half22float2(asH2(hr.z));
    const float2 r3 = __half22float2(asH2(hr.w));
    const float4 bi0 = *(const float4*)(bias + 8 * l);
    const float4 bi1 = *(const float4*)(bias + 8 * l + 4);
    float4 oA, oB;
    oA.x = c0 * inv + r0.x + bi0.x;
    oA.y = c1 * inv + r0.y + bi0.y;
    oA.z = c2 * inv + r1.x + bi0.z;
    oA.w = c3 * inv + r1.y + bi0.w;
    oB.x = c4 * inv + r2.x + bi1.x;
    oB.y = c5 * inv + r2.y + bi1.y;
    oB.z = c6 * inv + r3.x + bi1.z;
    oB.w = c7 * inv + r3.y + bi1.w;
    *(float4*)(out + (size_t)n * 32 + 8 * l) = oA;
    *(float4*)(out + (size_t)n * 32 + 8 * l + 4) = oB;
  }
}

// ---------------- CSR build: atomic-free radix partition (bucket-major cntmat) ----------------
__global__ __launch_bounds__(256)
void k_hist_chunk(const int* __restrict__ dst, int* __restrict__ cntmat,
                  int E, int NB, int NW) {
  __shared__ int lh[NBMAX];
  const int t = (int)threadIdx.x;
  const int chunk = (int)blockIdx.x;
  const int c0 = chunk * CHUNK;
  const int cnt = min(CHUNK, E - c0);
  for (int b = t; b < NB; b += 256) lh[b] = 0;
  __syncthreads();
  for (int i = t; i < cnt; i += 256)
    atomicAdd(&lh[dst[c0 + i] >> BSH], 1);
  __syncthreads();
  for (int b = t; b < NB; b += 256)
    cntmat[(size_t)b * NW + chunk] = lh[b];
}

template<int VPT>
__global__ __launch_bounds__(256)
void k_colscan(int* __restrict__ cntmat, int* __restrict__ bcnt, int NW) {
  __shared__ int sm[256];
  const int b = (int)blockIdx.x;
  int* row = cntmat + (size_t)b * NW;
  const int t = (int)threadIdx.x;
  int v[VPT];
  int run = 0;
  #pragma unroll
  for (int j = 0; j < VPT; ++j) {
    const int c = t * VPT + j;
    v[j] = (c < NW) ? row[c] : 0;
    run += v[j];
  }
  sm[t] = run;
  __syncthreads();
  #pragma unroll
  for (int off = 1; off < 256; off <<= 1) {
    int xv = (t >= off) ? sm[t - off] : 0;
    __syncthreads();
    sm[t] += xv;
    __syncthreads();
  }
  int excl = sm[t] - run;
  #pragma unroll
  for (int j = 0; j < VPT; ++j) {
    const int c = t * VPT + j;
    if (c < NW) row[c] = excl;
    excl += v[j];
  }
  if (t == 255) bcnt[b] = sm[255];
}

__global__ void k_bscan(const int* __restrict__ bcnt, int nb,
                        int* __restrict__ bstart, int* __restrict__ rowp_last, int E) {
  __shared__ int sm[256];
  const int t = (int)threadIdx.x;
  int v[4];
  #pragma unroll
  for (int j = 0; j < 4; ++j) { int i = t * 4 + j; v[j] = (i < nb) ? bcnt[i] : 0; }
  const int tot = v[0] + v[1] + v[2] + v[3];
  sm[t] = tot; __syncthreads();
  #pragma unroll
  for (int off = 1; off < 256; off <<= 1) {
    int xv = (t >= off) ? sm[t - off] : 0;
    __syncthreads();
    sm[t] += xv;
    __syncthreads();
  }
  int excl = sm[t] - tot;
  #pragma unroll
  for (int j = 0; j < 4; ++j) {
    int i = t * 4 + j;
    if (i < nb) { bstart[i] = excl; excl += v[j]; }
  }
  if (t == 0) { bstart[nb] = E; *rowp_last = E; }
}

__global__ __launch_bounds__(256)
void k_part(const int* __restrict__ src, const int* __restrict__ dst,
            const int* __restrict__ bstart, const int* __restrict__ cntmat,
            int* __restrict__ pairs, int E, int NB, int NW) {
  __shared__ int lh[NBMAX];
  __shared__ int lofs[NBMAX];
  __shared__ int gofs[NBMAX];
  __shared__ int stg[CHUNK];
  __shared__ short stgb[CHUNK];
  __shared__ int bsum[256];
  const int t = (int)threadIdx.x;
  const int chunk = (int)blockIdx.x;
  const int c0 = chunk * CHUNK;
  const int cnt = min(CHUNK, E - c0);

  for (int b = t; b < NB; b += 256) lh[b] = 0;
  __syncthreads();
  for (int i = t; i < cnt; i += 256)
    atomicAdd(&lh[dst[c0 + i] >> BSH], 1);
  __syncthreads();

  int v[4]; int run = 0;
  #pragma unroll
  for (int j = 0; j < 4; ++j) {
    const int b = t * 4 + j;
    v[j] = (b < NB) ? lh[b] : 0;
    run += v[j];
  }
  bsum[t] = run;
  __syncthreads();
  #pragma unroll
  for (int off = 1; off < 256; off <<= 1) {
    int xv = (t >= off) ? bsum[t - off] : 0;
    __syncthreads();
    bsum[t] += xv;
    __syncthreads();
  }
  int base = bsum[t] - run;
  #pragma unroll
  for (int j = 0; j < 4; ++j) {
    const int b = t * 4 + j;
    if (b < NB) lofs[b] = base;
    base += v[j];
  }
  __syncthreads();

  for (int b = t; b < NB; b += 256) {
    gofs[b] = bstart[b] + cntmat[(size_t)b * NW + chunk];
    lh[b] = lofs[b];
  }
  __syncthreads();

  for (int i = t; i < cnt; i += 256) {
    const int d = dst[c0 + i];
    const int b = d >> BSH;
    const int p = atomicAdd(&lh[b], 1);   // LDS only
    stg[p] = (src[c0 + i] << BSH) | (d & (BN - 1));
    stgb[p] = (short)b;
  }
  __syncthreads();

  for (int i = t; i < cnt; i += 256) {
    const int b = (int)stgb[i];
    pairs[gofs[b] + (i - lofs[b])] = stg[i];
  }
}

__global__ __launch_bounds__(256)
void k_bucket_csr(const int* __restrict__ pairs, const int* __restrict__ bstart,
                  int* __restrict__ rowp, int* __restrict__ col, int N) {
  __shared__ int ldeg[BN];
  __shared__ int lofs[BN];
  const int b = (int)blockIdx.x;
  const int t = (int)threadIdx.x;
  const int base = b << BSH;
  const int nn = min(BN, N - base);
  const int s0 = bstart[b];
  const int s1 = bstart[b + 1];

  if (t < BN) ldeg[t] = 0;
  __syncthreads();
  for (int i = s0 + t; i < s1; i += 256)
    atomicAdd(&ldeg[pairs[i] & (BN - 1)], 1);
  __syncthreads();
  if (t < BN) lofs[t] = ldeg[t];
  __syncthreads();
  #pragma unroll
  for (int off = 1; off < BN; off <<= 1) {
    int v = (t < BN && t >= off) ? lofs[t - off] : 0;
    __syncthreads();
    if (t < BN) lofs[t] += v;
    __syncthreads();
  }
  if (t < BN) {
    const int ofs = s0 + lofs[t] - ldeg[t];
    if (t < nn) rowp[base + t] = ofs;
    ldeg[t] = ofs;
  }
  __syncthreads();
  for (int i = s0 + t; i < s1; i += 256) {
    const int pr = pairs[i];
    const int p = atomicAdd(&ldeg[pr & (BN - 1)], 1);
    col[p] = pr >> BSH;
  }
}

extern "C" void kernel_launch(void* const* d_in, const int* in_sizes, int n_in,
                              void* d_out, int out_size, void* d_ws, size_t ws_size,
                              hipStream_t stream) {
  const float* x   = (const float*)d_in[0];
  const int* esrc  = (const int*)d_in[1];
  const int* edst  = (const int*)d_in[2];
  const float* W1  = (const float*)d_in[3];
  const float* as1 = (const float*)d_in[4];
  const float* ad1 = (const float*)d_in[5];
  const float* b1  = (const float*)d_in[6];
  const float* W2  = (const float*)d_in[7];
  const float* as2 = (const float*)d_in[8];
  const float* ad2 = (const float*)d_in[9];
  const float* b2  = (const float*)d_in[10];
  const float* W3  = (const float*)d_in[11];
  const float* as3 = (const float*)d_in[12];
  const float* ad3 = (const float*)d_in[13];
  const float* b3  = (const float*)d_in[14];
  const float* g1  = (const float*)d_in[15];
  const float* be1 = (const float*)d_in[16];
  const float* g2  = (const float*)d_in[17];
  const float* be2 = (const float*)d_in[18];

  const int N = in_sizes[0] / 128;
  const int E = in_sizes[1];
  const int NB = (N + BN - 1) / BN;
  const int NW = (E + CHUNK - 1) / CHUNK;

  char* ws = (char*)d_ws;
  size_t off = 0;
  auto alloc = [&](size_t bytes) -> void* {
    void* p = ws + off;
    off = (off + bytes + 255) & ~(size_t)255;
    return p;
  };
  __half* lnbuf = (__half*)alloc((size_t)N * 64 * 2);
  __half* hh   = (__half*)alloc((size_t)N * 64 * 2);
  float* sab   = (float*)alloc((size_t)N * 2 * 4);
  float* dab   = (float*)alloc((size_t)N * 2 * 4);
  int* rowp    = (int*)alloc((size_t)(N + 1) * 4);
  int* colb    = (int*)alloc((size_t)E * 4);
  int* bcnt    = (int*)alloc((size_t)NB * 4);
  int* bstart  = (int*)alloc((size_t)(NB + 1) * 4);
  int* cntmat  = (int*)alloc((size_t)NB * NW * 4);
  // pairs buffer: reuse d_out (N*32 floats = 12.8MB >= E*4 = 6.4MB);
  // lifetime ends before the final layer writes d_out.
  int* pairs = (E <= out_size) ? (int*)d_out : (int*)alloc((size_t)E * 4);
  (void)ws_size; (void)n_in;

  // ---- CSR build (zero global atomics) ----
  k_hist_chunk<<<NW, 256, 0, stream>>>(edst, cntmat, E, NB, NW);
  if (NW <= 512)        k_colscan<2><<<NB, 256, 0, stream>>>(cntmat, bcnt, NW);
  else if (NW <= 1024)  k_colscan<4><<<NB, 256, 0, stream>>>(cntmat, bcnt, NW);
  else                  k_colscan<8><<<NB, 256, 0, stream>>>(cntmat, bcnt, NW);
  k_bscan<<<1, 256, 0, stream>>>(bcnt, NB, bstart, rowp + N, E);
  k_part<<<NW, 256, 0, stream>>>(esrc, edst, bstart, cntmat, pairs, E, NB, NW);
  k_bucket_csr<<<NB, 256, 0, stream>>>(pairs, bstart, rowp, colb, N);

  const int gG12 = (N + 63) / 64;    // BM=64
  const int gG3  = (N + 127) / 128;  // BM=128
  const int gE2 = (N + 31) / 32;     // 8 nodes/wave * 4 waves/block
  const int gE1 = (N + 63) / 64;     // 16 nodes/wave * 4 waves/block

  // ---- Layer 1: 128 -> (2x32) + LN + ReLU ----
  gat_gemm4<128, 64, 2, true><<<gG12, 256, 0, stream>>>(x, W1, as1, ad1, hh, sab, dab, N);
  gat_edge2<<<gE2, 256, 0, stream>>>(hh, sab, dab, rowp, colb, b1, g1, be1, lnbuf, N);

  // ---- Layer 2: 64 -> (2x32) + LN + ReLU ----
  gat_gemm4<64, 64, 2, false><<<gG12, 256, 0, stream>>>(lnbuf, W2, as2, ad2, hh, sab, dab, N);
  gat_edge2<<<gE2, 256, 0, stream>>>(hh, sab, dab, rowp, colb, b2, g2, be2, lnbuf, N);

  // ---- Layer 3: 64 -> (1x32), no LN ----
  gat_gemm4<64, 32, 1, false><<<gG3, 256, 0, stream>>>(lnbuf, W3, as3, ad3, hh, sab, dab, N);
  gat_edge1<<<gE1, 256, 0, stream>>>(hh, sab, dab, rowp, colb, b3, (float*)d_out, N);
}

// Round 15
// 197.043 us; speedup vs baseline: 1.1002x; 1.1002x over previous
//
#include <hip/hip_runtime.h>
#include <hip/hip_fp16.h>

#define LEAKY 0.2f
#define BSH 7
#define BN 128      // nodes per bucket = 1<<BSH
#define CHUNK 4096  // edges per partition workgroup
#define NBMAX 1024  // max buckets supported by LDS arrays

__device__ __forceinline__ float leaky(float l) {
  return l >= 0.f ? l : LEAKY * l;
}

typedef _Float16 f16x8 __attribute__((ext_vector_type(8)));
typedef float f32x4 __attribute__((ext_vector_type(4)));

__device__ __forceinline__ int packsplat(float w) {
  const __half2 s = __half2half2(__float2half(w));
  return *(const int*)&s;
}
__device__ __forceinline__ __half2 asH2(unsigned u) { return *(__half2*)&u; }

// ---------------- MFMA GEMM: 4 waves x 16 node-rows, W fp16 in LDS ----------------
// A-frags (x) loaded DIRECT from global (no LDS round-trip, no barrier for x).
// Fragment layouts (gfx950 16x16x32): A/B: row|col = lane&15, k = (lane>>4)*8 + 0..7
// (contiguous); C/D: col = lane&15, row = (lane>>4)*4 + reg (m89/m91 verified).
template<int K, int CO, int H, bool IN_F32>
__global__ __launch_bounds__(256)
void gat_gemm5(const void* __restrict__ xin, const float* __restrict__ W,
               const float* __restrict__ atts, const float* __restrict__ attd,
               __half* __restrict__ hh, float* __restrict__ sa, float* __restrict__ da,
               int N) {
  constexpr int NT = CO / 16;   // column tiles (4 or 2)
  constexpr int KB = K / 32;    // k-steps (4 or 2)
  constexpr int LDH = K + 8;    // fp16 row stride (272B @ K=128) -> 2-way banks (free)
  constexpr int C = CO / H;

  __shared__ __half wsh[CO][LDH];

  const int t = (int)threadIdx.x;
  const int lane = t & 63;
  const int w = t >> 6;
  const int n0 = (int)blockIdx.x * 64;
  const int l15 = lane & 15;
  const int kofs = (lane >> 4) * 8;

  // ---- stage W (fp32 -> fp16 LDS) ----
  for (int f = t; f < CO * K / 4; f += 256) {
    const int r = f / (K / 4), c4 = f % (K / 4);
    const float4 v = *(const float4*)(W + (size_t)r * K + c4 * 4);
    *(__half2*)&wsh[r][c4 * 4]     = __floats2half2_rn(v.x, v.y);
    *(__half2*)&wsh[r][c4 * 4 + 2] = __floats2half2_rn(v.z, v.w);
  }

  // ---- A fragments direct from global ----
  int arow = n0 + 16 * w + l15;
  arow = arow < N ? arow : N - 1;
  f16x8 afr[KB];
  if constexpr (IN_F32) {
    const float* x = (const float*)xin;
    #pragma unroll
    for (int kb = 0; kb < KB; ++kb) {
      const float* p = x + (size_t)arow * K + kb * 32 + kofs;
      const float4 u = *(const float4*)p;
      const float4 v = *(const float4*)(p + 4);
      union { f16x8 f; __half2 h[4]; } U;
      U.h[0] = __floats2half2_rn(u.x, u.y);
      U.h[1] = __floats2half2_rn(u.z, u.w);
      U.h[2] = __floats2half2_rn(v.x, v.y);
      U.h[3] = __floats2half2_rn(v.z, v.w);
      afr[kb] = U.f;
    }
  } else {
    const __half* x = (const __half*)xin;
    #pragma unroll
    for (int kb = 0; kb < KB; ++kb)
      afr[kb] = *(const f16x8*)(x + (size_t)arow * K + kb * 32 + kofs);
  }
  __syncthreads();

  // ---- MFMA K-loop ----
  f32x4 acc[NT];
  #pragma unroll
  for (int tt = 0; tt < NT; ++tt) { f32x4 zf = {0.f, 0.f, 0.f, 0.f}; acc[tt] = zf; }
  #pragma unroll
  for (int kb = 0; kb < KB; ++kb) {
    #pragma unroll
    for (int tt = 0; tt < NT; ++tt) {
      const f16x8 bfr = *(const f16x8*)&wsh[16 * tt + l15][kb * 32 + kofs];
      acc[tt] = __builtin_amdgcn_mfma_f32_16x16x32_f16(afr[kb], bfr, acc[tt], 0, 0, 0);
    }
  }

  // ---- epilogue: fused sa/da + fp16 h store ----
  float as_[NT], ad_[NT];
  #pragma unroll
  for (int tt = 0; tt < NT; ++tt) {
    as_[tt] = atts[16 * tt + l15];
    ad_[tt] = attd[16 * tt + l15];
  }
  float ps[4][H] = {}, pd[4][H] = {};
  #pragma unroll
  for (int tt = 0; tt < NT; ++tt) {
    const int hd = (16 * tt) / C;
    #pragma unroll
    for (int r = 0; r < 4; ++r) {
      ps[r][hd] = fmaf(acc[tt][r], as_[tt], ps[r][hd]);
      pd[r][hd] = fmaf(acc[tt][r], ad_[tt], pd[r][hd]);
    }
  }
  #pragma unroll
  for (int m = 1; m < 16; m <<= 1) {
    #pragma unroll
    for (int r = 0; r < 4; ++r) {
      #pragma unroll
      for (int hd = 0; hd < H; ++hd) {
        ps[r][hd] += __shfl_xor(ps[r][hd], m, 64);
        pd[r][hd] += __shfl_xor(pd[r][hd], m, 64);
      }
    }
  }

  const int obase = n0 + 16 * w + ((lane >> 4) << 2);
  #pragma unroll
  for (int r = 0; r < 4; ++r) {
    const int node = obase + r;
    if (node < N) {
      #pragma unroll
      for (int tt = 0; tt < NT; ++tt)
        hh[(size_t)node * CO + 16 * tt + l15] = __float2half(acc[tt][r]);
      if (l15 == 0) {
        #pragma unroll
        for (int hd = 0; hd < H; ++hd) {
          sa[node * H + hd] = ps[r][hd];
          da[node * H + hd] = pd[r][hd];
        }
      }
    }
  }
}

// ---------------- Edge aggregation, H=2 (64 ch): 8 nodes/wave, 16B/lane ----------------
__global__ __launch_bounds__(256)
void gat_edge2(const __half* __restrict__ hh,
               const float* __restrict__ sa, const float* __restrict__ da,
               const int* __restrict__ rowp, const int* __restrict__ col,
               const float* __restrict__ bias, const float* __restrict__ gamma,
               const float* __restrict__ beta, __half* __restrict__ out, int N) {
  __shared__ int2 wst[4][8][9][2];    // [wave][oct][edge(8)+pad][head]
  const int t = (int)threadIdx.x;
  const int lane = t & 63;
  const int wib = t >> 6;
  const int oct = lane >> 3;
  const int l = lane & 7;             // channels 8l .. 8l+7
  const int headq = l >> 2;
  const int wgl = (int)((blockIdx.x * blockDim.x + t) >> 6);
  const int n = wgl * 8 + oct;
  const bool valid = (n < N);
  const int nc = valid ? n : N - 1;
  const int beg = rowp[nc];
  const int end = rowp[nc + 1];
  const float2 dvv = *(const float2*)(da + (size_t)nc * 2);
  const __half* __restrict__ hp = hh;

  const __half2 z = __float2half2_rn(0.f);
  __half2 A0 = z, A1 = z, A2 = z, A3 = z;
  __half2 B0 = z, B1 = z, B2 = z, B3 = z;
  __half2 qA = z, qB = z;

  int sP = 0; float2 pP = make_float2(0.f, 0.f);
  if (beg < end) {
    const int c0 = min(8, end - beg);
    if (l < c0) { sP = col[beg + l]; pP = *(const float2*)(sa + (size_t)sP * 2); }
  }

  for (int b0 = beg; b0 < end; b0 += 8) {
    const int cnt = min(8, end - b0);
    if (l < cnt) {
      int2 e0; e0.x = sP; e0.y = packsplat(__expf(leaky(pP.x + dvv.x)));
      int2 e1; e1.x = sP; e1.y = packsplat(__expf(leaky(pP.y + dvv.y)));
      wst[wib][oct][l][0] = e0;
      wst[wib][oct][l][1] = e1;
    }
    const int nb0 = b0 + 8;
    if (nb0 < end) {
      const int ncnt = min(8, end - nb0);
      if (l < ncnt) { sP = col[nb0 + l]; pP = *(const float2*)(sa + (size_t)sP * 2); }
    }
    int i = 0;
    for (; i + 4 <= cnt; i += 4) {
      const int2 e0 = wst[wib][oct][i][headq];
      const int2 e1 = wst[wib][oct][i + 1][headq];
      const int2 e2 = wst[wib][oct][i + 2][headq];
      const int2 e3 = wst[wib][oct][i + 3][headq];
      const uint4 h0 = *(const uint4*)(hp + ((size_t)e0.x << 6) + 8 * l);
      const uint4 h1 = *(const uint4*)(hp + ((size_t)e1.x << 6) + 8 * l);
      const uint4 h2 = *(const uint4*)(hp + ((size_t)e2.x << 6) + 8 * l);
      const uint4 h3 = *(const uint4*)(hp + ((size_t)e3.x << 6) + 8 * l);
      const __half2 w0 = asH2(e0.y), w1 = asH2(e1.y), w2 = asH2(e2.y), w3 = asH2(e3.y);
      qA = __hadd2(qA, __hadd2(w0, w1));
      qB = __hadd2(qB, __hadd2(w2, w3));
      A0 = __hfma2(w0, asH2(h0.x), A0); A1 = __hfma2(w0, asH2(h0.y), A1);
      A2 = __hfma2(w0, asH2(h0.z), A2); A3 = __hfma2(w0, asH2(h0.w), A3);
      B0 = __hfma2(w1, asH2(h1.x), B0); B1 = __hfma2(w1, asH2(h1.y), B1);
      B2 = __hfma2(w1, asH2(h1.z), B2); B3 = __hfma2(w1, asH2(h1.w), B3);
      A0 = __hfma2(w2, asH2(h2.x), A0); A1 = __hfma2(w2, asH2(h2.y), A1);
      A2 = __hfma2(w2, asH2(h2.z), A2); A3 = __hfma2(w2, asH2(h2.w), A3);
      B0 = __hfma2(w3, asH2(h3.x), B0); B1 = __hfma2(w3, asH2(h3.y), B1);
      B2 = __hfma2(w3, asH2(h3.z), B2); B3 = __hfma2(w3, asH2(h3.w), B3);
    }
    for (; i < cnt; ++i) {
      const int2 e = wst[wib][oct][i][headq];
      const uint4 hv = *(const uint4*)(hp + ((size_t)e.x << 6) + 8 * l);
      const __half2 w = asH2(e.y);
      qA = __hadd2(qA, w);
      A0 = __hfma2(w, asH2(hv.x), A0); A1 = __hfma2(w, asH2(hv.y), A1);
      A2 = __hfma2(w, asH2(hv.z), A2); A3 = __hfma2(w, asH2(hv.w), A3);
    }
  }

  const float c0 = __low2float(A0) + __low2float(B0);
  const float c1 = __high2float(A0) + __high2float(B0);
  const float c2 = __low2float(A1) + __low2float(B1);
  const float c3 = __high2float(A1) + __high2float(B1);
  const float c4 = __low2float(A2) + __low2float(B2);
  const float c5 = __high2float(A2) + __high2float(B2);
  const float c6 = __low2float(A3) + __low2float(B3);
  const float c7 = __high2float(A3) + __high2float(B3);
  const float qf = __low2float(qA) + __low2float(qB);

  const float inv = 1.f / fmaxf(qf, 1e-16f);
  const uint4 hr = *(const uint4*)(hp + ((size_t)nc << 6) + 8 * l);
  const float2 r0 = __half22float2(asH2(hr.x));
  const float2 r1 = __half22float2(asH2(hr.y));
  const float2 r2 = __half22float2(asH2(hr.z));
  const float2 r3 = __half22float2(asH2(hr.w));
  const float4 bi0 = *(const float4*)(bias + 8 * l);
  const float4 bi1 = *(const float4*)(bias + 8 * l + 4);
  float v0 = c0 * inv + r0.x + bi0.x;
  float v1 = c1 * inv + r0.y + bi0.y;
  float v2 = c2 * inv + r1.x + bi0.z;
  float v3 = c3 * inv + r1.y + bi0.w;
  float v4 = c4 * inv + r2.x + bi1.x;
  float v5 = c5 * inv + r2.y + bi1.y;
  float v6 = c6 * inv + r3.x + bi1.z;
  float v7 = c7 * inv + r3.y + bi1.w;
  {
    float s = ((v0 + v1) + (v2 + v3)) + ((v4 + v5) + (v6 + v7));
    s += __shfl_xor(s, 1, 64); s += __shfl_xor(s, 2, 64); s += __shfl_xor(s, 4, 64);
    const float mu = s * (1.f / 64.f);
    const float d0 = v0 - mu, d1 = v1 - mu, d2 = v2 - mu, d3 = v3 - mu;
    const float d4 = v4 - mu, d5 = v5 - mu, d6 = v6 - mu, d7 = v7 - mu;
    float vs = ((d0 * d0 + d1 * d1) + (d2 * d2 + d3 * d3)) +
               ((d4 * d4 + d5 * d5) + (d6 * d6 + d7 * d7));
    vs += __shfl_xor(vs, 1, 64); vs += __shfl_xor(vs, 2, 64); vs += __shfl_xor(vs, 4, 64);
    const float rs = rsqrtf(vs * (1.f / 64.f) + 1e-5f);
    const float4 g0 = *(const float4*)(gamma + 8 * l);
    const float4 g1 = *(const float4*)(gamma + 8 * l + 4);
    const float4 e0 = *(const float4*)(beta + 8 * l);
    const float4 e1 = *(const float4*)(beta + 8 * l + 4);
    v0 = fmaxf(d0 * rs * g0.x + e0.x, 0.f);
    v1 = fmaxf(d1 * rs * g0.y + e0.y, 0.f);
    v2 = fmaxf(d2 * rs * g0.z + e0.z, 0.f);
    v3 = fmaxf(d3 * rs * g0.w + e0.w, 0.f);
    v4 = fmaxf(d4 * rs * g1.x + e1.x, 0.f);
    v5 = fmaxf(d5 * rs * g1.y + e1.y, 0.f);
    v6 = fmaxf(d6 * rs * g1.z + e1.z, 0.f);
    v7 = fmaxf(d7 * rs * g1.w + e1.w, 0.f);
  }
  if (valid) {
    const __half2 o0 = __floats2half2_rn(v0, v1);
    const __half2 o1 = __floats2half2_rn(v2, v3);
    const __half2 o2 = __floats2half2_rn(v4, v5);
    const __half2 o3 = __floats2half2_rn(v6, v7);
    uint4 o;
    o.x = *(const unsigned*)&o0; o.y = *(const unsigned*)&o1;
    o.z = *(const unsigned*)&o2; o.w = *(const unsigned*)&o3;
    *(uint4*)(out + (size_t)n * 64 + 8 * l) = o;
  }
}

// ---------------- Edge aggregation, H=1 (32 ch): 16 nodes/wave, 16B/lane ----------------
__global__ __launch_bounds__(256)
void gat_edge1(const __half* __restrict__ hh,
               const float* __restrict__ sa, const float* __restrict__ da,
               const int* __restrict__ rowp, const int* __restrict__ col,
               const float* __restrict__ bias, float* __restrict__ out, int N) {
  __shared__ int2 wst[4][16][5];      // [wave][node(16)][edge(4)+pad]
  const int t = (int)threadIdx.x;
  const int lane = t & 63;
  const int wib = t >> 6;
  const int nq = lane >> 2;           // node within wave
  const int l = lane & 3;             // channels 8l .. 8l+7
  const int wgl = (int)((blockIdx.x * blockDim.x + t) >> 6);
  const int n = wgl * 16 + nq;
  const bool valid = (n < N);
  const int nc = valid ? n : N - 1;
  const int beg = rowp[nc];
  const int end = rowp[nc + 1];
  const float dv = da[nc];
  const __half* __restrict__ hp = hh;

  const __half2 z = __float2half2_rn(0.f);
  __half2 A0 = z, A1 = z, A2 = z, A3 = z;
  __half2 B0 = z, B1 = z, B2 = z, B3 = z;
  __half2 qA = z, qB = z;

  int sP = 0; float pP = 0.f;
  if (beg < end) {
    const int c0 = min(4, end - beg);
    if (l < c0) { sP = col[beg + l]; pP = sa[sP]; }
  }

  for (int b0 = beg; b0 < end; b0 += 4) {
    const int cnt = min(4, end - b0);
    if (l < cnt) {
      int2 e; e.x = sP; e.y = packsplat(__expf(leaky(pP + dv)));
      wst[wib][nq][l] = e;
    }
    const int nb0 = b0 + 4;
    if (nb0 < end) {
      const int ncnt = min(4, end - nb0);
      if (l < ncnt) { sP = col[nb0 + l]; pP = sa[sP]; }
    }
    if (cnt == 4) {
      const int2 e0 = wst[wib][nq][0];
      const int2 e1 = wst[wib][nq][1];
      const int2 e2 = wst[wib][nq][2];
      const int2 e3 = wst[wib][nq][3];
      const uint4 h0 = *(const uint4*)(hp + ((size_t)e0.x << 5) + 8 * l);
      const uint4 h1 = *(const uint4*)(hp + ((size_t)e1.x << 5) + 8 * l);
      const uint4 h2 = *(const uint4*)(hp + ((size_t)e2.x << 5) + 8 * l);
      const uint4 h3 = *(const uint4*)(hp + ((size_t)e3.x << 5) + 8 * l);
      const __half2 w0 = asH2(e0.y), w1 = asH2(e1.y), w2 = asH2(e2.y), w3 = asH2(e3.y);
      qA = __hadd2(qA, __hadd2(w0, w1));
      qB = __hadd2(qB, __hadd2(w2, w3));
      A0 = __hfma2(w0, asH2(h0.x), A0); A1 = __hfma2(w0, asH2(h0.y), A1);
      A2 = __hfma2(w0, asH2(h0.z), A2); A3 = __hfma2(w0, asH2(h0.w), A3);
      B0 = __hfma2(w1, asH2(h1.x), B0); B1 = __hfma2(w1, asH2(h1.y), B1);
      B2 = __hfma2(w1, asH2(h1.z), B2); B3 = __hfma2(w1, asH2(h1.w), B3);
      A0 = __hfma2(w2, asH2(h2.x), A0); A1 = __hfma2(w2, asH2(h2.y), A1);
      A2 = __hfma2(w2, asH2(h2.z), A2); A3 = __hfma2(w2, asH2(h2.w), A3);
      B0 = __hfma2(w3, asH2(h3.x), B0); B1 = __hfma2(w3, asH2(h3.y), B1);
      B2 = __hfma2(w3, asH2(h3.z), B2); B3 = __hfma2(w3, asH2(h3.w), B3);
    } else {
      for (int i = 0; i < cnt; ++i) {
        const int2 e = wst[wib][nq][i];
        const uint4 hv = *(const uint4*)(hp + ((size_t)e.x << 5) + 8 * l);
        const __half2 w = asH2(e.y);
        qA = __hadd2(qA, w);
        A0 = __hfma2(w, asH2(hv.x), A0); A1 = __hfma2(w, asH2(hv.y), A1);
        A2 = __hfma2(w, asH2(hv.z), A2); A3 = __hfma2(w, asH2(hv.w), A3);
      }
    }
  }

  if (valid) {
    const float c0 = __low2float(A0) + __low2float(B0);
    const float c1 = __high2float(A0) + __high2float(B0);
    const float c2 = __low2float(A1) + __low2float(B1);
    const float c3 = __high2float(A1) + __high2float(B1);
    const float c4 = __low2float(A2) + __low2float(B2);
    const float c5 = __high2float(A2) + __high2float(B2);
    const float c6 = __low2float(A3) + __low2float(B3);
    const float c7 = __high2float(A3) + __high2float(B3);
    const float qf = __low2float(qA) + __low2float(qB);
    const float inv = 1.f / fmaxf(qf, 1e-16f);
    const uint4 hr = *(const uint4*)(hp + ((size_t)nc << 5) + 8 * l);
    const float2 r0 = __half22float2(asH2(hr.x));
    const float2 r1 = __half22float2(asH2(hr.y));
    const float2 r2 = __half22float2(asH2(hr.z));
    const float2 r3 = __half22float2(asH2(hr.w));
    const float4 bi0 = *(const float4*)(bias + 8 * l);
    const float4 bi1 = *(const float4*)(bias + 8 * l + 4);
    float4 oA, oB;
    oA.x = c0 * inv + r0.x + bi0.x;
    oA.y = c1 * inv + r0.y + bi0.y;
    oA.z = c2 * inv + r1.x + bi0.z;
    oA.w = c3 * inv + r1.y + bi0.w;
    oB.x = c4 * inv + r2.x + bi1.x;
    oB.y = c5 * inv + r2.y + bi1.y;
    oB.z = c6 * inv + r3.x + bi1.z;
    oB.w = c7 * inv + r3.y + bi1.w;
    *(float4*)(out + (size_t)n * 32 + 8 * l) = oA;
    *(float4*)(out + (size_t)n * 32 + 8 * l + 4) = oB;
  }
}

// ---------------- CSR build: atomic-free radix partition (bucket-major cntmat) ----------------
__global__ __launch_bounds__(256)
void k_hist_chunk(const int* __restrict__ dst, int* __restrict__ cntmat,
                  int E, int NB, int NW) {
  __shared__ int lh[NBMAX];
  const int t = (int)threadIdx.x;
  const int chunk = (int)blockIdx.x;
  const int c0 = chunk * CHUNK;
  const int cnt = min(CHUNK, E - c0);
  for (int b = t; b < NB; b += 256) lh[b] = 0;
  __syncthreads();
  for (int i = t; i < cnt; i += 256)
    atomicAdd(&lh[dst[c0 + i] >> BSH], 1);
  __syncthreads();
  for (int b = t; b < NB; b += 256)
    cntmat[(size_t)b * NW + chunk] = lh[b];
}

template<int VPT>
__global__ __launch_bounds__(256)
void k_colscan(int* __restrict__ cntmat, int* __restrict__ bcnt, int NW) {
  __shared__ int sm[256];
  const int b = (int)blockIdx.x;
  int* row = cntmat + (size_t)b * NW;
  const int t = (int)threadIdx.x;
  int v[VPT];
  int run = 0;
  #pragma unroll
  for (int j = 0; j < VPT; ++j) {
    const int c = t * VPT + j;
    v[j] = (c < NW) ? row[c] : 0;
    run += v[j];
  }
  sm[t] = run;
  __syncthreads();
  #pragma unroll
  for (int off = 1; off < 256; off <<= 1) {
    int xv = (t >= off) ? sm[t - off] : 0;
    __syncthreads();
    sm[t] += xv;
    __syncthreads();
  }
  int excl = sm[t] - run;
  #pragma unroll
  for (int j = 0; j < VPT; ++j) {
    const int c = t * VPT + j;
    if (c < NW) row[c] = excl;
    excl += v[j];
  }
  if (t == 255) bcnt[b] = sm[255];
}

__global__ void k_bscan(const int* __restrict__ bcnt, int nb,
                        int* __restrict__ bstart, int* __restrict__ rowp_last, int E) {
  __shared__ int sm[256];
  const int t = (int)threadIdx.x;
  int v[4];
  #pragma unroll
  for (int j = 0; j < 4; ++j) { int i = t * 4 + j; v[j] = (i < nb) ? bcnt[i] : 0; }
  const int tot = v[0] + v[1] + v[2] + v[3];
  sm[t] = tot; __syncthreads();
  #pragma unroll
  for (int off = 1; off < 256; off <<= 1) {
    int xv = (t >= off) ? sm[t - off] : 0;
    __syncthreads();
    sm[t] += xv;
    __syncthreads();
  }
  int excl = sm[t] - tot;
  #pragma unroll
  for (int j = 0; j < 4; ++j) {
    int i = t * 4 + j;
    if (i < nb) { bstart[i] = excl; excl += v[j]; }
  }
  if (t == 0) { bstart[nb] = E; *rowp_last = E; }
}

__global__ __launch_bounds__(256)
void k_part(const int* __restrict__ src, const int* __restrict__ dst,
            const int* __restrict__ bstart, const int* __restrict__ cntmat,
            int* __restrict__ pairs, int E, int NB, int NW) {
  __shared__ int lh[NBMAX];
  __shared__ int lofs[NBMAX];
  __shared__ int gofs[NBMAX];
  __shared__ int stg[CHUNK];
  __shared__ short stgb[CHUNK];
  __shared__ int bsum[256];
  const int t = (int)threadIdx.x;
  const int chunk = (int)blockIdx.x;
  const int c0 = chunk * CHUNK;
  const int cnt = min(CHUNK, E - c0);

  for (int b = t; b < NB; b += 256) lh[b] = 0;
  __syncthreads();
  for (int i = t; i < cnt; i += 256)
    atomicAdd(&lh[dst[c0 + i] >> BSH], 1);
  __syncthreads();

  int v[4]; int run = 0;
  #pragma unroll
  for (int j = 0; j < 4; ++j) {
    const int b = t * 4 + j;
    v[j] = (b < NB) ? lh[b] : 0;
    run += v[j];
  }
  bsum[t] = run;
  __syncthreads();
  #pragma unroll
  for (int off = 1; off < 256; off <<= 1) {
    int xv = (t >= off) ? bsum[t - off] : 0;
    __syncthreads();
    bsum[t] += xv;
    __syncthreads();
  }
  int base = bsum[t] - run;
  #pragma unroll
  for (int j = 0; j < 4; ++j) {
    const int b = t * 4 + j;
    if (b < NB) lofs[b] = base;
    base += v[j];
  }
  __syncthreads();

  for (int b = t; b < NB; b += 256) {
    gofs[b] = bstart[b] + cntmat[(size_t)b * NW + chunk];
    lh[b] = lofs[b];
  }
  __syncthreads();

  for (int i = t; i < cnt; i += 256) {
    const int d = dst[c0 + i];
    const int b = d >> BSH;
    const int p = atomicAdd(&lh[b], 1);   // LDS only
    stg[p] = (src[c0 + i] << BSH) | (d & (BN - 1));
    stgb[p] = (short)b;
  }
  __syncthreads();

  for (int i = t; i < cnt; i += 256) {
    const int b = (int)stgb[i];
    pairs[gofs[b] + (i - lofs[b])] = stg[i];
  }
}

__global__ __launch_bounds__(256)
void k_bucket_csr(const int* __restrict__ pairs, const int* __restrict__ bstart,
                  int* __restrict__ rowp, int* __restrict__ col, int N) {
  __shared__ int ldeg[BN];
  __shared__ int lofs[BN];
  const int b = (int)blockIdx.x;
  const int t = (int)threadIdx.x;
  const int base = b << BSH;
  const int nn = min(BN, N - base);
  const int s0 = bstart[b];
  const int s1 = bstart[b + 1];

  if (t < BN) ldeg[t] = 0;
  __syncthreads();
  for (int i = s0 + t; i < s1; i += 256)
    atomicAdd(&ldeg[pairs[i] & (BN - 1)], 1);
  __syncthreads();
  if (t < BN) lofs[t] = ldeg[t];
  __syncthreads();
  #pragma unroll
  for (int off = 1; off < BN; off <<= 1) {
    int v = (t < BN && t >= off) ? lofs[t - off] : 0;
    __syncthreads();
    if (t < BN) lofs[t] += v;
    __syncthreads();
  }
  if (t < BN) {
    const int ofs = s0 + lofs[t] - ldeg[t];
    if (t < nn) rowp[base + t] = ofs;
    ldeg[t] = ofs;
  }
  __syncthreads();
  for (int i = s0 + t; i < s1; i += 256) {
    const int pr = pairs[i];
    const int p = atomicAdd(&ldeg[pr & (BN - 1)], 1);
    col[p] = pr >> BSH;
  }
}

extern "C" void kernel_launch(void* const* d_in, const int* in_sizes, int n_in,
                              void* d_out, int out_size, void* d_ws, size_t ws_size,
                              hipStream_t stream) {
  const float* x   = (const float*)d_in[0];
  const int* esrc  = (const int*)d_in[1];
  const int* edst  = (const int*)d_in[2];
  const float* W1  = (const float*)d_in[3];
  const float* as1 = (const float*)d_in[4];
  const float* ad1 = (const float*)d_in[5];
  const float* b1  = (const float*)d_in[6];
  const float* W2  = (const float*)d_in[7];
  const float* as2 = (const float*)d_in[8];
  const float* ad2 = (const float*)d_in[9];
  const float* b2  = (const float*)d_in[10];
  const float* W3  = (const float*)d_in[11];
  const float* as3 = (const float*)d_in[12];
  const float* ad3 = (const float*)d_in[13];
  const float* b3  = (const float*)d_in[14];
  const float* g1  = (const float*)d_in[15];
  const float* be1 = (const float*)d_in[16];
  const float* g2  = (const float*)d_in[17];
  const float* be2 = (const float*)d_in[18];

  const int N = in_sizes[0] / 128;
  const int E = in_sizes[1];
  const int NB = (N + BN - 1) / BN;
  const int NW = (E + CHUNK - 1) / CHUNK;

  char* ws = (char*)d_ws;
  size_t off = 0;
  auto alloc = [&](size_t bytes) -> void* {
    void* p = ws + off;
    off = (off + bytes + 255) & ~(size_t)255;
    return p;
  };
  __half* lnbuf = (__half*)alloc((size_t)N * 64 * 2);
  __half* hh   = (__half*)alloc((size_t)N * 64 * 2);
  float* sab   = (float*)alloc((size_t)N * 2 * 4);
  float* dab   = (float*)alloc((size_t)N * 2 * 4);
  int* rowp    = (int*)alloc((size_t)(N + 1) * 4);
  int* colb    = (int*)alloc((size_t)E * 4);
  int* bcnt    = (int*)alloc((size_t)NB * 4);
  int* bstart  = (int*)alloc((size_t)(NB + 1) * 4);
  int* cntmat  = (int*)alloc((size_t)NB * NW * 4);
  // pairs buffer: reuse d_out (N*32 floats = 12.8MB >= E*4 = 6.4MB);
  // lifetime ends before the final layer writes d_out.
  int* pairs = (E <= out_size) ? (int*)d_out : (int*)alloc((size_t)E * 4);
  (void)ws_size; (void)n_in;

  // ---- CSR build (zero global atomics) ----
  k_hist_chunk<<<NW, 256, 0, stream>>>(edst, cntmat, E, NB, NW);
  if (NW <= 512)        k_colscan<2><<<NB, 256, 0, stream>>>(cntmat, bcnt, NW);
  else if (NW <= 1024)  k_colscan<4><<<NB, 256, 0, stream>>>(cntmat, bcnt, NW);
  else                  k_colscan<8><<<NB, 256, 0, stream>>>(cntmat, bcnt, NW);
  k_bscan<<<1, 256, 0, stream>>>(bcnt, NB, bstart, rowp + N, E);
  k_part<<<NW, 256, 0, stream>>>(esrc, edst, bstart, cntmat, pairs, E, NB, NW);
  k_bucket_csr<<<NB, 256, 0, stream>>>(pairs, bstart, rowp, colb, N);

  const int gG  = (N + 63) / 64;     // 64 nodes per block (all layers)
  const int gE2 = (N + 31) / 32;     // 8 nodes/wave * 4 waves/block
  const int gE1 = (N + 63) / 64;     // 16 nodes/wave * 4 waves/block

  // ---- Layer 1: 128 -> (2x32) + LN + ReLU ----
  gat_gemm5<128, 64, 2, true><<<gG, 256, 0, stream>>>(x, W1, as1, ad1, hh, sab, dab, N);
  gat_edge2<<<gE2, 256, 0, stream>>>(hh, sab, dab, rowp, colb, b1, g1, be1, lnbuf, N);

  // ---- Layer 2: 64 -> (2x32) + LN + ReLU ----
  gat_gemm5<64, 64, 2, false><<<gG, 256, 0, stream>>>(lnbuf, W2, as2, ad2, hh, sab, dab, N);
  gat_edge2<<<gE2, 256, 0, stream>>>(hh, sab, dab, rowp, colb, b2, g2, be2, lnbuf, N);

  // ---- Layer 3: 64 -> (1x32), no LN ----
  gat_gemm5<64, 32, 1, false><<<gG, 256, 0, stream>>>(lnbuf, W3, as3, ad3, hh, sab, dab, N);
  gat_edge1<<<gE1, 256, 0, stream>>>(hh, sab, dab, rowp, colb, b3, (float*)d_out, N);
}

// Round 16
// 196.695 us; speedup vs baseline: 1.1022x; 1.0018x over previous
//
#include <hip/hip_runtime.h>
#include <hip/hip_fp16.h>

#define LEAKY 0.2f
#define BSH 7
#define BN 128      // nodes per bucket = 1<<BSH
#define CHUNK 4096  // edges per partition workgroup
#define NBMAX 1024  // max buckets supported by LDS arrays

__device__ __forceinline__ float leaky(float l) {
  return l >= 0.f ? l : LEAKY * l;
}

typedef _Float16 f16x8 __attribute__((ext_vector_type(8)));
typedef float f32x4 __attribute__((ext_vector_type(4)));

__device__ __forceinline__ int packsplat(float w) {
  const __half2 s = __half2half2(__float2half(w));
  return *(const int*)&s;
}
__device__ __forceinline__ __half2 asH2(unsigned u) { return *(__half2*)&u; }

// ---------------- MFMA GEMM: 4 waves x 16 node-rows, W fp16 in LDS ----------------
// A-frags (x) loaded DIRECT from global (no LDS round-trip, no barrier for x).
// Fragment layouts (gfx950 16x16x32): A/B: row|col = lane&15, k = (lane>>4)*8 + 0..7
// (contiguous); C/D: col = lane&15, row = (lane>>4)*4 + reg (m89/m91 verified).
template<int K, int CO, int H, bool IN_F32>
__global__ __launch_bounds__(256)
void gat_gemm5(const void* __restrict__ xin, const float* __restrict__ W,
               const float* __restrict__ atts, const float* __restrict__ attd,
               __half* __restrict__ hh, float* __restrict__ sa, float* __restrict__ da,
               int N) {
  constexpr int NT = CO / 16;   // column tiles (4 or 2)
  constexpr int KB = K / 32;    // k-steps (4 or 2)
  constexpr int LDH = K + 8;    // fp16 row stride (272B @ K=128) -> 2-way banks (free)
  constexpr int C = CO / H;

  __shared__ __half wsh[CO][LDH];

  const int t = (int)threadIdx.x;
  const int lane = t & 63;
  const int w = t >> 6;
  const int n0 = (int)blockIdx.x * 64;
  const int l15 = lane & 15;
  const int kofs = (lane >> 4) * 8;

  // ---- stage W (fp32 -> fp16 LDS) ----
  for (int f = t; f < CO * K / 4; f += 256) {
    const int r = f / (K / 4), c4 = f % (K / 4);
    const float4 v = *(const float4*)(W + (size_t)r * K + c4 * 4);
    *(__half2*)&wsh[r][c4 * 4]     = __floats2half2_rn(v.x, v.y);
    *(__half2*)&wsh[r][c4 * 4 + 2] = __floats2half2_rn(v.z, v.w);
  }

  // ---- A fragments direct from global ----
  int arow = n0 + 16 * w + l15;
  arow = arow < N ? arow : N - 1;
  f16x8 afr[KB];
  if constexpr (IN_F32) {
    const float* x = (const float*)xin;
    #pragma unroll
    for (int kb = 0; kb < KB; ++kb) {
      const float* p = x + (size_t)arow * K + kb * 32 + kofs;
      const float4 u = *(const float4*)p;
      const float4 v = *(const float4*)(p + 4);
      union { f16x8 f; __half2 h[4]; } U;
      U.h[0] = __floats2half2_rn(u.x, u.y);
      U.h[1] = __floats2half2_rn(u.z, u.w);
      U.h[2] = __floats2half2_rn(v.x, v.y);
      U.h[3] = __floats2half2_rn(v.z, v.w);
      afr[kb] = U.f;
    }
  } else {
    const __half* x = (const __half*)xin;
    #pragma unroll
    for (int kb = 0; kb < KB; ++kb)
      afr[kb] = *(const f16x8*)(x + (size_t)arow * K + kb * 32 + kofs);
  }
  __syncthreads();

  // ---- MFMA K-loop ----
  f32x4 acc[NT];
  #pragma unroll
  for (int tt = 0; tt < NT; ++tt) { f32x4 zf = {0.f, 0.f, 0.f, 0.f}; acc[tt] = zf; }
  #pragma unroll
  for (int kb = 0; kb < KB; ++kb) {
    #pragma unroll
    for (int tt = 0; tt < NT; ++tt) {
      const f16x8 bfr = *(const f16x8*)&wsh[16 * tt + l15][kb * 32 + kofs];
      acc[tt] = __builtin_amdgcn_mfma_f32_16x16x32_f16(afr[kb], bfr, acc[tt], 0, 0, 0);
    }
  }

  // ---- epilogue: fused sa/da + fp16 h store ----
  float as_[NT], ad_[NT];
  #pragma unroll
  for (int tt = 0; tt < NT; ++tt) {
    as_[tt] = atts[16 * tt + l15];
    ad_[tt] = attd[16 * tt + l15];
  }
  float ps[4][H] = {}, pd[4][H] = {};
  #pragma unroll
  for (int tt = 0; tt < NT; ++tt) {
    const int hd = (16 * tt) / C;
    #pragma unroll
    for (int r = 0; r < 4; ++r) {
      ps[r][hd] = fmaf(acc[tt][r], as_[tt], ps[r][hd]);
      pd[r][hd] = fmaf(acc[tt][r], ad_[tt], pd[r][hd]);
    }
  }
  #pragma unroll
  for (int m = 1; m < 16; m <<= 1) {
    #pragma unroll
    for (int r = 0; r < 4; ++r) {
      #pragma unroll
      for (int hd = 0; hd < H; ++hd) {
        ps[r][hd] += __shfl_xor(ps[r][hd], m, 64);
        pd[r][hd] += __shfl_xor(pd[r][hd], m, 64);
      }
    }
  }

  const int obase = n0 + 16 * w + ((lane >> 4) << 2);
  #pragma unroll
  for (int r = 0; r < 4; ++r) {
    const int node = obase + r;
    if (node < N) {
      #pragma unroll
      for (int tt = 0; tt < NT; ++tt)
        hh[(size_t)node * CO + 16 * tt + l15] = __float2half(acc[tt][r]);
      if (l15 == 0) {
        #pragma unroll
        for (int hd = 0; hd < H; ++hd) {
          sa[node * H + hd] = ps[r][hd];
          da[node * H + hd] = pd[r][hd];
        }
      }
    }
  }
}

// ---------------- Edge aggregation, H=2 (64 ch): 8 nodes/wave, 16B/lane ----------------
__global__ __launch_bounds__(256)
void gat_edge2(const __half* __restrict__ hh,
               const float* __restrict__ sa, const float* __restrict__ da,
               const int* __restrict__ rowp, const int* __restrict__ col,
               const float* __restrict__ bias, const float* __restrict__ gamma,
               const float* __restrict__ beta, __half* __restrict__ out, int N) {
  __shared__ int2 wst[4][8][9][2];    // [wave][oct][edge(8)+pad][head]
  const int t = (int)threadIdx.x;
  const int lane = t & 63;
  const int wib = t >> 6;
  const int oct = lane >> 3;
  const int l = lane & 7;             // channels 8l .. 8l+7
  const int headq = l >> 2;
  const int wgl = (int)((blockIdx.x * blockDim.x + t) >> 6);
  const int n = wgl * 8 + oct;
  const bool valid = (n < N);
  const int nc = valid ? n : N - 1;
  const int beg = rowp[nc];
  const int end = rowp[nc + 1];
  const float2 dvv = *(const float2*)(da + (size_t)nc * 2);
  const __half* __restrict__ hp = hh;

  const __half2 z = __float2half2_rn(0.f);
  __half2 A0 = z, A1 = z, A2 = z, A3 = z;
  __half2 B0 = z, B1 = z, B2 = z, B3 = z;
  __half2 qA = z, qB = z;

  int sP = 0; float2 pP = make_float2(0.f, 0.f);
  if (beg < end) {
    const int c0 = min(8, end - beg);
    if (l < c0) { sP = col[beg + l]; pP = *(const float2*)(sa + (size_t)sP * 2); }
  }

  for (int b0 = beg; b0 < end; b0 += 8) {
    const int cnt = min(8, end - b0);
    if (l < cnt) {
      int2 e0; e0.x = sP; e0.y = packsplat(__expf(leaky(pP.x + dvv.x)));
      int2 e1; e1.x = sP; e1.y = packsplat(__expf(leaky(pP.y + dvv.y)));
      wst[wib][oct][l][0] = e0;
      wst[wib][oct][l][1] = e1;
    }
    const int nb0 = b0 + 8;
    if (nb0 < end) {
      const int ncnt = min(8, end - nb0);
      if (l < ncnt) { sP = col[nb0 + l]; pP = *(const float2*)(sa + (size_t)sP * 2); }
    }
    int i = 0;
    for (; i + 4 <= cnt; i += 4) {
      const int2 e0 = wst[wib][oct][i][headq];
      const int2 e1 = wst[wib][oct][i + 1][headq];
      const int2 e2 = wst[wib][oct][i + 2][headq];
      const int2 e3 = wst[wib][oct][i + 3][headq];
      const uint4 h0 = *(const uint4*)(hp + ((size_t)e0.x << 6) + 8 * l);
      const uint4 h1 = *(const uint4*)(hp + ((size_t)e1.x << 6) + 8 * l);
      const uint4 h2 = *(const uint4*)(hp + ((size_t)e2.x << 6) + 8 * l);
      const uint4 h3 = *(const uint4*)(hp + ((size_t)e3.x << 6) + 8 * l);
      const __half2 w0 = asH2(e0.y), w1 = asH2(e1.y), w2 = asH2(e2.y), w3 = asH2(e3.y);
      qA = __hadd2(qA, __hadd2(w0, w1));
      qB = __hadd2(qB, __hadd2(w2, w3));
      A0 = __hfma2(w0, asH2(h0.x), A0); A1 = __hfma2(w0, asH2(h0.y), A1);
      A2 = __hfma2(w0, asH2(h0.z), A2); A3 = __hfma2(w0, asH2(h0.w), A3);
      B0 = __hfma2(w1, asH2(h1.x), B0); B1 = __hfma2(w1, asH2(h1.y), B1);
      B2 = __hfma2(w1, asH2(h1.z), B2); B3 = __hfma2(w1, asH2(h1.w), B3);
      A0 = __hfma2(w2, asH2(h2.x), A0); A1 = __hfma2(w2, asH2(h2.y), A1);
      A2 = __hfma2(w2, asH2(h2.z), A2); A3 = __hfma2(w2, asH2(h2.w), A3);
      B0 = __hfma2(w3, asH2(h3.x), B0); B1 = __hfma2(w3, asH2(h3.y), B1);
      B2 = __hfma2(w3, asH2(h3.z), B2); B3 = __hfma2(w3, asH2(h3.w), B3);
    }
    for (; i < cnt; ++i) {
      const int2 e = wst[wib][oct][i][headq];
      const uint4 hv = *(const uint4*)(hp + ((size_t)e.x << 6) + 8 * l);
      const __half2 w = asH2(e.y);
      qA = __hadd2(qA, w);
      A0 = __hfma2(w, asH2(hv.x), A0); A1 = __hfma2(w, asH2(hv.y), A1);
      A2 = __hfma2(w, asH2(hv.z), A2); A3 = __hfma2(w, asH2(hv.w), A3);
    }
  }

  const float c0 = __low2float(A0) + __low2float(B0);
  const float c1 = __high2float(A0) + __high2float(B0);
  const float c2 = __low2float(A1) + __low2float(B1);
  const float c3 = __high2float(A1) + __high2float(B1);
  const float c4 = __low2float(A2) + __low2float(B2);
  const float c5 = __high2float(A2) + __high2float(B2);
  const float c6 = __low2float(A3) + __low2float(B3);
  const float c7 = __high2float(A3) + __high2float(B3);
  const float qf = __low2float(qA) + __low2float(qB);

  const float inv = 1.f / fmaxf(qf, 1e-16f);
  const uint4 hr = *(const uint4*)(hp + ((size_t)nc << 6) + 8 * l);
  const float2 r0 = __half22float2(asH2(hr.x));
  const float2 r1 = __half22float2(asH2(hr.y));
  const float2 r2 = __half22float2(asH2(hr.z));
  const float2 r3 = __half22float2(asH2(hr.w));
  const float4 bi0 = *(const float4*)(bias + 8 * l);
  const float4 bi1 = *(const float4*)(bias + 8 * l + 4);
  float v0 = c0 * inv + r0.x + bi0.x;
  float v1 = c1 * inv + r0.y + bi0.y;
  float v2 = c2 * inv + r1.x + bi0.z;
  float v3 = c3 * inv + r1.y + bi0.w;
  float v4 = c4 * inv + r2.x + bi1.x;
  float v5 = c5 * inv + r2.y + bi1.y;
  float v6 = c6 * inv + r3.x + bi1.z;
  float v7 = c7 * inv + r3.y + bi1.w;
  {
    float s = ((v0 + v1) + (v2 + v3)) + ((v4 + v5) + (v6 + v7));
    s += __shfl_xor(s, 1, 64); s += __shfl_xor(s, 2, 64); s += __shfl_xor(s, 4, 64);
    const float mu = s * (1.f / 64.f);
    const float d0 = v0 - mu, d1 = v1 - mu, d2 = v2 - mu, d3 = v3 - mu;
    const float d4 = v4 - mu, d5 = v5 - mu, d6 = v6 - mu, d7 = v7 - mu;
    float vs = ((d0 * d0 + d1 * d1) + (d2 * d2 + d3 * d3)) +
               ((d4 * d4 + d5 * d5) + (d6 * d6 + d7 * d7));
    vs += __shfl_xor(vs, 1, 64); vs += __shfl_xor(vs, 2, 64); vs += __shfl_xor(vs, 4, 64);
    const float rs = rsqrtf(vs * (1.f / 64.f) + 1e-5f);
    const float4 g0 = *(const float4*)(gamma + 8 * l);
    const float4 g1 = *(const float4*)(gamma + 8 * l + 4);
    const float4 e0 = *(const float4*)(beta + 8 * l);
    const float4 e1 = *(const float4*)(beta + 8 * l + 4);
    v0 = fmaxf(d0 * rs * g0.x + e0.x, 0.f);
    v1 = fmaxf(d1 * rs * g0.y + e0.y, 0.f);
    v2 = fmaxf(d2 * rs * g0.z + e0.z, 0.f);
    v3 = fmaxf(d3 * rs * g0.w + e0.w, 0.f);
    v4 = fmaxf(d4 * rs * g1.x + e1.x, 0.f);
    v5 = fmaxf(d5 * rs * g1.y + e1.y, 0.f);
    v6 = fmaxf(d6 * rs * g1.z + e1.z, 0.f);
    v7 = fmaxf(d7 * rs * g1.w + e1.w, 0.f);
  }
  if (valid) {
    const __half2 o0 = __floats2half2_rn(v0, v1);
    const __half2 o1 = __floats2half2_rn(v2, v3);
    const __half2 o2 = __floats2half2_rn(v4, v5);
    const __half2 o3 = __floats2half2_rn(v6, v7);
    uint4 o;
    o.x = *(const unsigned*)&o0; o.y = *(const unsigned*)&o1;
    o.z = *(const unsigned*)&o2; o.w = *(const unsigned*)&o3;
    *(uint4*)(out + (size_t)n * 64 + 8 * l) = o;
  }
}

// ---------------- Edge aggregation, H=1 (32 ch): 16 nodes/wave, 16B/lane ----------------
__global__ __launch_bounds__(256)
void gat_edge1(const __half* __restrict__ hh,
               const float* __restrict__ sa, const float* __restrict__ da,
               const int* __restrict__ rowp, const int* __restrict__ col,
               const float* __restrict__ bias, float* __restrict__ out, int N) {
  __shared__ int2 wst[4][16][5];      // [wave][node(16)][edge(4)+pad]
  const int t = (int)threadIdx.x;
  const int lane = t & 63;
  const int wib = t >> 6;
  const int nq = lane >> 2;           // node within wave
  const int l = lane & 3;             // channels 8l .. 8l+7
  const int wgl = (int)((blockIdx.x * blockDim.x + t) >> 6);
  const int n = wgl * 16 + nq;
  const bool valid = (n < N);
  const int nc = valid ? n : N - 1;
  const int beg = rowp[nc];
  const int end = rowp[nc + 1];
  const float dv = da[nc];
  const __half* __restrict__ hp = hh;

  const __half2 z = __float2half2_rn(0.f);
  __half2 A0 = z, A1 = z, A2 = z, A3 = z;
  __half2 B0 = z, B1 = z, B2 = z, B3 = z;
  __half2 qA = z, qB = z;

  int sP = 0; float pP = 0.f;
  if (beg < end) {
    const int c0 = min(4, end - beg);
    if (l < c0) { sP = col[beg + l]; pP = sa[sP]; }
  }

  for (int b0 = beg; b0 < end; b0 += 4) {
    const int cnt = min(4, end - b0);
    if (l < cnt) {
      int2 e; e.x = sP; e.y = packsplat(__expf(leaky(pP + dv)));
      wst[wib][nq][l] = e;
    }
    const int nb0 = b0 + 4;
    if (nb0 < end) {
      const int ncnt = min(4, end - nb0);
      if (l < ncnt) { sP = col[nb0 + l]; pP = sa[sP]; }
    }
    if (cnt == 4) {
      const int2 e0 = wst[wib][nq][0];
      const int2 e1 = wst[wib][nq][1];
      const int2 e2 = wst[wib][nq][2];
      const int2 e3 = wst[wib][nq][3];
      const uint4 h0 = *(const uint4*)(hp + ((size_t)e0.x << 5) + 8 * l);
      const uint4 h1 = *(const uint4*)(hp + ((size_t)e1.x << 5) + 8 * l);
      const uint4 h2 = *(const uint4*)(hp + ((size_t)e2.x << 5) + 8 * l);
      const uint4 h3 = *(const uint4*)(hp + ((size_t)e3.x << 5) + 8 * l);
      const __half2 w0 = asH2(e0.y), w1 = asH2(e1.y), w2 = asH2(e2.y), w3 = asH2(e3.y);
      qA = __hadd2(qA, __hadd2(w0, w1));
      qB = __hadd2(qB, __hadd2(w2, w3));
      A0 = __hfma2(w0, asH2(h0.x), A0); A1 = __hfma2(w0, asH2(h0.y), A1);
      A2 = __hfma2(w0, asH2(h0.z), A2); A3 = __hfma2(w0, asH2(h0.w), A3);
      B0 = __hfma2(w1, asH2(h1.x), B0); B1 = __hfma2(w1, asH2(h1.y), B1);
      B2 = __hfma2(w1, asH2(h1.z), B2); B3 = __hfma2(w1, asH2(h1.w), B3);
      A0 = __hfma2(w2, asH2(h2.x), A0); A1 = __hfma2(w2, asH2(h2.y), A1);
      A2 = __hfma2(w2, asH2(h2.z), A2); A3 = __hfma2(w2, asH2(h2.w), A3);
      B0 = __hfma2(w3, asH2(h3.x), B0); B1 = __hfma2(w3, asH2(h3.y), B1);
      B2 = __hfma2(w3, asH2(h3.z), B2); B3 = __hfma2(w3, asH2(h3.w), B3);
    } else {
      for (int i = 0; i < cnt; ++i) {
        const int2 e = wst[wib][nq][i];
        const uint4 hv = *(const uint4*)(hp + ((size_t)e.x << 5) + 8 * l);
        const __half2 w = asH2(e.y);
        qA = __hadd2(qA, w);
        A0 = __hfma2(w, asH2(hv.x), A0); A1 = __hfma2(w, asH2(hv.y), A1);
        A2 = __hfma2(w, asH2(hv.z), A2); A3 = __hfma2(w, asH2(hv.w), A3);
      }
    }
  }

  if (valid) {
    const float c0 = __low2float(A0) + __low2float(B0);
    const float c1 = __high2float(A0) + __high2float(B0);
    const float c2 = __low2float(A1) + __low2float(B1);
    const float c3 = __high2float(A1) + __high2float(B1);
    const float c4 = __low2float(A2) + __low2float(B2);
    const float c5 = __high2float(A2) + __high2float(B2);
    const float c6 = __low2float(A3) + __low2float(B3);
    const float c7 = __high2float(A3) + __high2float(B3);
    const float qf = __low2float(qA) + __low2float(qB);
    const float inv = 1.f / fmaxf(qf, 1e-16f);
    const uint4 hr = *(const uint4*)(hp + ((size_t)nc << 5) + 8 * l);
    const float2 r0 = __half22float2(asH2(hr.x));
    const float2 r1 = __half22float2(asH2(hr.y));
    const float2 r2 = __half22float2(asH2(hr.z));
    const float2 r3 = __half22float2(asH2(hr.w));
    const float4 bi0 = *(const float4*)(bias + 8 * l);
    const float4 bi1 = *(const float4*)(bias + 8 * l + 4);
    float4 oA, oB;
    oA.x = c0 * inv + r0.x + bi0.x;
    oA.y = c1 * inv + r0.y + bi0.y;
    oA.z = c2 * inv + r1.x + bi0.z;
    oA.w = c3 * inv + r1.y + bi0.w;
    oB.x = c4 * inv + r2.x + bi1.x;
    oB.y = c5 * inv + r2.y + bi1.y;
    oB.z = c6 * inv + r3.x + bi1.z;
    oB.w = c7 * inv + r3.y + bi1.w;
    *(float4*)(out + (size_t)n * 32 + 8 * l) = oA;
    *(float4*)(out + (size_t)n * 32 + 8 * l + 4) = oB;
  }
}

// ---------------- CSR build: atomic-free radix partition (bucket-major cntmat) ----------------
__global__ __launch_bounds__(256)
void k_hist_chunk(const int* __restrict__ dst, int* __restrict__ cntmat,
                  int E, int NB, int NW) {
  __shared__ int lh[NBMAX];
  const int t = (int)threadIdx.x;
  const int chunk = (int)blockIdx.x;
  const int c0 = chunk * CHUNK;
  const int cnt = min(CHUNK, E - c0);
  for (int b = t; b < NB; b += 256) lh[b] = 0;
  __syncthreads();
  for (int i = t; i < cnt; i += 256)
    atomicAdd(&lh[dst[c0 + i] >> BSH], 1);
  __syncthreads();
  for (int b = t; b < NB; b += 256)
    cntmat[(size_t)b * NW + chunk] = lh[b];
}

template<int VPT>
__global__ __launch_bounds__(256)
void k_colscan(int* __restrict__ cntmat, int* __restrict__ bcnt, int NW) {
  __shared__ int sm[256];
  const int b = (int)blockIdx.x;
  int* row = cntmat + (size_t)b * NW;
  const int t = (int)threadIdx.x;
  int v[VPT];
  int run = 0;
  #pragma unroll
  for (int j = 0; j < VPT; ++j) {
    const int c = t * VPT + j;
    v[j] = (c < NW) ? row[c] : 0;
    run += v[j];
  }
  sm[t] = run;
  __syncthreads();
  #pragma unroll
  for (int off = 1; off < 256; off <<= 1) {
    int xv = (t >= off) ? sm[t - off] : 0;
    __syncthreads();
    sm[t] += xv;
    __syncthreads();
  }
  int excl = sm[t] - run;
  #pragma unroll
  for (int j = 0; j < VPT; ++j) {
    const int c = t * VPT + j;
    if (c < NW) row[c] = excl;
    excl += v[j];
  }
  if (t == 255) bcnt[b] = sm[255];
}

__global__ void k_bscan(const int* __restrict__ bcnt, int nb,
                        int* __restrict__ bstart, int* __restrict__ rowp_last, int E) {
  __shared__ int sm[256];
  const int t = (int)threadIdx.x;
  int v[4];
  #pragma unroll
  for (int j = 0; j < 4; ++j) { int i = t * 4 + j; v[j] = (i < nb) ? bcnt[i] : 0; }
  const int tot = v[0] + v[1] + v[2] + v[3];
  sm[t] = tot; __syncthreads();
  #pragma unroll
  for (int off = 1; off < 256; off <<= 1) {
    int xv = (t >= off) ? sm[t - off] : 0;
    __syncthreads();
    sm[t] += xv;
    __syncthreads();
  }
  int excl = sm[t] - tot;
  #pragma unroll
  for (int j = 0; j < 4; ++j) {
    int i = t * 4 + j;
    if (i < nb) { bstart[i] = excl; excl += v[j]; }
  }
  if (t == 0) { bstart[nb] = E; *rowp_last = E; }
}

__global__ __launch_bounds__(256)
void k_part(const int* __restrict__ src, const int* __restrict__ dst,
            const int* __restrict__ bstart, const int* __restrict__ cntmat,
            int* __restrict__ pairs, int E, int NB, int NW) {
  __shared__ int lh[NBMAX];
  __shared__ int lofs[NBMAX];
  __shared__ int gofs[NBMAX];
  __shared__ int stg[CHUNK];
  __shared__ short stgb[CHUNK];
  __shared__ int bsum[256];
  const int t = (int)threadIdx.x;
  const int chunk = (int)blockIdx.x;
  const int c0 = chunk * CHUNK;
  const int cnt = min(CHUNK, E - c0);

  for (int b = t; b < NB; b += 256) lh[b] = 0;
  __syncthreads();
  for (int i = t; i < cnt; i += 256)
    atomicAdd(&lh[dst[c0 + i] >> BSH], 1);
  __syncthreads();

  int v[4]; int run = 0;
  #pragma unroll
  for (int j = 0; j < 4; ++j) {
    const int b = t * 4 + j;
    v[j] = (b < NB) ? lh[b] : 0;
    run += v[j];
  }
  bsum[t] = run;
  __syncthreads();
  #pragma unroll
  for (int off = 1; off < 256; off <<= 1) {
    int xv = (t >= off) ? bsum[t - off] : 0;
    __syncthreads();
    bsum[t] += xv;
    __syncthreads();
  }
  int base = bsum[t] - run;
  #pragma unroll
  for (int j = 0; j < 4; ++j) {
    const int b = t * 4 + j;
    if (b < NB) lofs[b] = base;
    base += v[j];
  }
  __syncthreads();

  for (int b = t; b < NB; b += 256) {
    gofs[b] = bstart[b] + cntmat[(size_t)b * NW + chunk];
    lh[b] = lofs[b];
  }
  __syncthreads();

  for (int i = t; i < cnt; i += 256) {
    const int d = dst[c0 + i];
    const int b = d >> BSH;
    const int p = atomicAdd(&lh[b], 1);   // LDS only
    stg[p] = (src[c0 + i] << BSH) | (d & (BN - 1));
    stgb[p] = (short)b;
  }
  __syncthreads();

  for (int i = t; i < cnt; i += 256) {
    const int b = (int)stgb[i];
    pairs[gofs[b] + (i - lofs[b])] = stg[i];
  }
}

__global__ __launch_bounds__(256)
void k_bucket_csr(const int* __restrict__ pairs, const int* __restrict__ bstart,
                  int* __restrict__ rowp, int* __restrict__ col, int N) {
  __shared__ int ldeg[BN];
  __shared__ int lofs[BN];
  const int b = (int)blockIdx.x;
  const int t = (int)threadIdx.x;
  const int base = b << BSH;
  const int nn = min(BN, N - base);
  const int s0 = bstart[b];
  const int s1 = bstart[b + 1];

  if (t < BN) ldeg[t] = 0;
  __syncthreads();
  for (int i = s0 + t; i < s1; i += 256)
    atomicAdd(&ldeg[pairs[i] & (BN - 1)], 1);
  __syncthreads();
  if (t < BN) lofs[t] = ldeg[t];
  __syncthreads();
  #pragma unroll
  for (int off = 1; off < BN; off <<= 1) {
    int v = (t < BN && t >= off) ? lofs[t - off] : 0;
    __syncthreads();
    if (t < BN) lofs[t] += v;
    __syncthreads();
  }
  if (t < BN) {
    const int ofs = s0 + lofs[t] - ldeg[t];
    if (t < nn) rowp[base + t] = ofs;
    ldeg[t] = ofs;
  }
  __syncthreads();
  for (int i = s0 + t; i < s1; i += 256) {
    const int pr = pairs[i];
    const int p = atomicAdd(&ldeg[pr & (BN - 1)], 1);
    col[p] = pr >> BSH;
  }
}

extern "C" void kernel_launch(void* const* d_in, const int* in_sizes, int n_in,
                              void* d_out, int out_size, void* d_ws, size_t ws_size,
                              hipStream_t stream) {
  const float* x   = (const float*)d_in[0];
  const int* esrc  = (const int*)d_in[1];
  const int* edst  = (const int*)d_in[2];
  const float* W1  = (const float*)d_in[3];
  const float* as1 = (const float*)d_in[4];
  const float* ad1 = (const float*)d_in[5];
  const float* b1  = (const float*)d_in[6];
  const float* W2  = (const float*)d_in[7];
  const float* as2 = (const float*)d_in[8];
  const float* ad2 = (const float*)d_in[9];
  const float* b2  = (const float*)d_in[10];
  const float* W3  = (const float*)d_in[11];
  const float* as3 = (const float*)d_in[12];
  const float* ad3 = (const float*)d_in[13];
  const float* b3  = (const float*)d_in[14];
  const float* g1  = (const float*)d_in[15];
  const float* be1 = (const float*)d_in[16];
  const float* g2  = (const float*)d_in[17];
  const float* be2 = (const float*)d_in[18];

  const int N = in_sizes[0] / 128;
  const int E = in_sizes[1];
  const int NB = (N + BN - 1) / BN;
  const int NW = (E + CHUNK - 1) / CHUNK;

  char* ws = (char*)d_ws;
  size_t off = 0;
  auto alloc = [&](size_t bytes) -> void* {
    void* p = ws + off;
    off = (off + bytes + 255) & ~(size_t)255;
    return p;
  };
  __half* lnbuf = (__half*)alloc((size_t)N * 64 * 2);
  __half* hh   = (__half*)alloc((size_t)N * 64 * 2);
  float* sab   = (float*)alloc((size_t)N * 2 * 4);
  float* dab   = (float*)alloc((size_t)N * 2 * 4);
  int* rowp    = (int*)alloc((size_t)(N + 1) * 4);
  int* colb    = (int*)alloc((size_t)E * 4);
  int* bcnt    = (int*)alloc((size_t)NB * 4);
  int* bstart  = (int*)alloc((size_t)(NB + 1) * 4);
  int* cntmat  = (int*)alloc((size_t)NB * NW * 4);
  // pairs buffer: reuse d_out (N*32 floats = 12.8MB >= E*4 = 6.4MB);
  // lifetime ends before the final layer writes d_out.
  int* pairs = (E <= out_size) ? (int*)d_out : (int*)alloc((size_t)E * 4);
  (void)ws_size; (void)n_in;

  // ---- CSR build (zero global atomics) ----
  k_hist_chunk<<<NW, 256, 0, stream>>>(edst, cntmat, E, NB, NW);
  if (NW <= 512)        k_colscan<2><<<NB, 256, 0, stream>>>(cntmat, bcnt, NW);
  else if (NW <= 1024)  k_colscan<4><<<NB, 256, 0, stream>>>(cntmat, bcnt, NW);
  else                  k_colscan<8><<<NB, 256, 0, stream>>>(cntmat, bcnt, NW);
  k_bscan<<<1, 256, 0, stream>>>(bcnt, NB, bstart, rowp + N, E);
  k_part<<<NW, 256, 0, stream>>>(esrc, edst, bstart, cntmat, pairs, E, NB, NW);
  k_bucket_csr<<<NB, 256, 0, stream>>>(pairs, bstart, rowp, colb, N);

  const int gG  = (N + 63) / 64;     // 64 nodes per block (all layers)
  const int gE2 = (N + 31) / 32;     // 8 nodes/wave * 4 waves/block
  const int gE1 = (N + 63) / 64;     // 16 nodes/wave * 4 waves/block

  // ---- Layer 1: 128 -> (2x32) + LN + ReLU ----
  gat_gemm5<128, 64, 2, true><<<gG, 256, 0, stream>>>(x, W1, as1, ad1, hh, sab, dab, N);
  gat_edge2<<<gE2, 256, 0, stream>>>(hh, sab, dab, rowp, colb, b1, g1, be1, lnbuf, N);

  // ---- Layer 2: 64 -> (2x32) + LN + ReLU ----
  gat_gemm5<64, 64, 2, false><<<gG, 256, 0, stream>>>(lnbuf, W2, as2, ad2, hh, sab, dab, N);
  gat_edge2<<<gE2, 256, 0, stream>>>(hh, sab, dab, rowp, colb, b2, g2, be2, lnbuf, N);

  // ---- Layer 3: 64 -> (1x32), no LN ----
  gat_gemm5<64, 32, 1, false><<<gG, 256, 0, stream>>>(lnbuf, W3, as3, ad3, hh, sab, dab, N);
  gat_edge1<<<gE1, 256, 0, stream>>>(hh, sab, dab, rowp, colb, b3, (float*)d_out, N);
}

// Round 17
// 196.677 us; speedup vs baseline: 1.1023x; 1.0001x over previous
//
#include <hip/hip_runtime.h>
#include <hip/hip_fp16.h>

#define LEAKY 0.2f
#define BSH 7
#define BN 128      // nodes per bucket = 1<<BSH
#define CHUNK 4096  // edges per partition workgroup
#define NBMAX 1024  // max buckets supported by LDS arrays

__device__ __forceinline__ float leaky(float l) {
  return l >= 0.f ? l : LEAKY * l;
}

typedef _Float16 f16x8 __attribute__((ext_vector_type(8)));
typedef float f32x4 __attribute__((ext_vector_type(4)));

__device__ __forceinline__ int packsplat(float w) {
  const __half2 s = __half2half2(__float2half(w));
  return *(const int*)&s;
}
__device__ __forceinline__ __half2 asH2(unsigned u) { return *(__half2*)&u; }

// ---------------- MFMA GEMM: 4 waves x 16 node-rows, W fp16 in LDS ----------------
// A-frags (x) loaded DIRECT from global (no LDS round-trip, no barrier for x).
// Fragment layouts (gfx950 16x16x32): A/B: row|col = lane&15, k = (lane>>4)*8 + 0..7
// (contiguous); C/D: col = lane&15, row = (lane>>4)*4 + reg (m89/m91 verified).
template<int K, int CO, int H, bool IN_F32>
__global__ __launch_bounds__(256)
void gat_gemm5(const void* __restrict__ xin, const float* __restrict__ W,
               const float* __restrict__ atts, const float* __restrict__ attd,
               __half* __restrict__ hh, float* __restrict__ sa, float* __restrict__ da,
               int N) {
  constexpr int NT = CO / 16;   // column tiles (4 or 2)
  constexpr int KB = K / 32;    // k-steps (4 or 2)
  constexpr int LDH = K + 8;    // fp16 row stride (272B @ K=128) -> 2-way banks (free)
  constexpr int C = CO / H;

  __shared__ __half wsh[CO][LDH];

  const int t = (int)threadIdx.x;
  const int lane = t & 63;
  const int w = t >> 6;
  const int n0 = (int)blockIdx.x * 64;
  const int l15 = lane & 15;
  const int kofs = (lane >> 4) * 8;

  // ---- stage W (fp32 -> fp16 LDS) ----
  for (int f = t; f < CO * K / 4; f += 256) {
    const int r = f / (K / 4), c4 = f % (K / 4);
    const float4 v = *(const float4*)(W + (size_t)r * K + c4 * 4);
    *(__half2*)&wsh[r][c4 * 4]     = __floats2half2_rn(v.x, v.y);
    *(__half2*)&wsh[r][c4 * 4 + 2] = __floats2half2_rn(v.z, v.w);
  }

  // ---- A fragments direct from global ----
  int arow = n0 + 16 * w + l15;
  arow = arow < N ? arow : N - 1;
  f16x8 afr[KB];
  if constexpr (IN_F32) {
    const float* x = (const float*)xin;
    #pragma unroll
    for (int kb = 0; kb < KB; ++kb) {
      const float* p = x + (size_t)arow * K + kb * 32 + kofs;
      const float4 u = *(const float4*)p;
      const float4 v = *(const float4*)(p + 4);
      union { f16x8 f; __half2 h[4]; } U;
      U.h[0] = __floats2half2_rn(u.x, u.y);
      U.h[1] = __floats2half2_rn(u.z, u.w);
      U.h[2] = __floats2half2_rn(v.x, v.y);
      U.h[3] = __floats2half2_rn(v.z, v.w);
      afr[kb] = U.f;
    }
  } else {
    const __half* x = (const __half*)xin;
    #pragma unroll
    for (int kb = 0; kb < KB; ++kb)
      afr[kb] = *(const f16x8*)(x + (size_t)arow * K + kb * 32 + kofs);
  }
  __syncthreads();

  // ---- MFMA K-loop ----
  f32x4 acc[NT];
  #pragma unroll
  for (int tt = 0; tt < NT; ++tt) { f32x4 zf = {0.f, 0.f, 0.f, 0.f}; acc[tt] = zf; }
  #pragma unroll
  for (int kb = 0; kb < KB; ++kb) {
    #pragma unroll
    for (int tt = 0; tt < NT; ++tt) {
      const f16x8 bfr = *(const f16x8*)&wsh[16 * tt + l15][kb * 32 + kofs];
      acc[tt] = __builtin_amdgcn_mfma_f32_16x16x32_f16(afr[kb], bfr, acc[tt], 0, 0, 0);
    }
  }

  // ---- epilogue: fused sa/da + fp16 h store ----
  float as_[NT], ad_[NT];
  #pragma unroll
  for (int tt = 0; tt < NT; ++tt) {
    as_[tt] = atts[16 * tt + l15];
    ad_[tt] = attd[16 * tt + l15];
  }
  float ps[4][H] = {}, pd[4][H] = {};
  #pragma unroll
  for (int tt = 0; tt < NT; ++tt) {
    const int hd = (16 * tt) / C;
    #pragma unroll
    for (int r = 0; r < 4; ++r) {
      ps[r][hd] = fmaf(acc[tt][r], as_[tt], ps[r][hd]);
      pd[r][hd] = fmaf(acc[tt][r], ad_[tt], pd[r][hd]);
    }
  }
  #pragma unroll
  for (int m = 1; m < 16; m <<= 1) {
    #pragma unroll
    for (int r = 0; r < 4; ++r) {
      #pragma unroll
      for (int hd = 0; hd < H; ++hd) {
        ps[r][hd] += __shfl_xor(ps[r][hd], m, 64);
        pd[r][hd] += __shfl_xor(pd[r][hd], m, 64);
      }
    }
  }

  const int obase = n0 + 16 * w + ((lane >> 4) << 2);
  #pragma unroll
  for (int r = 0; r < 4; ++r) {
    const int node = obase + r;
    if (node < N) {
      #pragma unroll
      for (int tt = 0; tt < NT; ++tt)
        hh[(size_t)node * CO + 16 * tt + l15] = __float2half(acc[tt][r]);
      if (l15 == 0) {
        #pragma unroll
        for (int hd = 0; hd < H; ++hd) {
          sa[node * H + hd] = ps[r][hd];
          da[node * H + hd] = pd[r][hd];
        }
      }
    }
  }
}

// ---------------- Edge aggregation, H=2 (64 ch): 8 nodes/wave, 16B/lane ----------------
__global__ __launch_bounds__(256)
void gat_edge2(const __half* __restrict__ hh,
               const float* __restrict__ sa, const float* __restrict__ da,
               const int* __restrict__ rowp, const int* __restrict__ col,
               const float* __restrict__ bias, const float* __restrict__ gamma,
               const float* __restrict__ beta, __half* __restrict__ out, int N) {
  __shared__ int2 wst[4][8][9][2];    // [wave][oct][edge(8)+pad][head]
  const int t = (int)threadIdx.x;
  const int lane = t & 63;
  const int wib = t >> 6;
  const int oct = lane >> 3;
  const int l = lane & 7;             // channels 8l .. 8l+7
  const int headq = l >> 2;
  const int wgl = (int)((blockIdx.x * blockDim.x + t) >> 6);
  const int n = wgl * 8 + oct;
  const bool valid = (n < N);
  const int nc = valid ? n : N - 1;
  const int beg = rowp[nc];
  const int end = rowp[nc + 1];
  const float2 dvv = *(const float2*)(da + (size_t)nc * 2);
  const __half* __restrict__ hp = hh;

  const __half2 z = __float2half2_rn(0.f);
  __half2 A0 = z, A1 = z, A2 = z, A3 = z;
  __half2 B0 = z, B1 = z, B2 = z, B3 = z;
  __half2 qA = z, qB = z;

  int sP = 0; float2 pP = make_float2(0.f, 0.f);
  if (beg < end) {
    const int c0 = min(8, end - beg);
    if (l < c0) { sP = col[beg + l]; pP = *(const float2*)(sa + (size_t)sP * 2); }
  }

  for (int b0 = beg; b0 < end; b0 += 8) {
    const int cnt = min(8, end - b0);
    if (l < cnt) {
      int2 e0; e0.x = sP; e0.y = packsplat(__expf(leaky(pP.x + dvv.x)));
      int2 e1; e1.x = sP; e1.y = packsplat(__expf(leaky(pP.y + dvv.y)));
      wst[wib][oct][l][0] = e0;
      wst[wib][oct][l][1] = e1;
    }
    const int nb0 = b0 + 8;
    if (nb0 < end) {
      const int ncnt = min(8, end - nb0);
      if (l < ncnt) { sP = col[nb0 + l]; pP = *(const float2*)(sa + (size_t)sP * 2); }
    }
    int i = 0;
    for (; i + 4 <= cnt; i += 4) {
      const int2 e0 = wst[wib][oct][i][headq];
      const int2 e1 = wst[wib][oct][i + 1][headq];
      const int2 e2 = wst[wib][oct][i + 2][headq];
      const int2 e3 = wst[wib][oct][i + 3][headq];
      const uint4 h0 = *(const uint4*)(hp + ((size_t)e0.x << 6) + 8 * l);
      const uint4 h1 = *(const uint4*)(hp + ((size_t)e1.x << 6) + 8 * l);
      const uint4 h2 = *(const uint4*)(hp + ((size_t)e2.x << 6) + 8 * l);
      const uint4 h3 = *(const uint4*)(hp + ((size_t)e3.x << 6) + 8 * l);
      const __half2 w0 = asH2(e0.y), w1 = asH2(e1.y), w2 = asH2(e2.y), w3 = asH2(e3.y);
      qA = __hadd2(qA, __hadd2(w0, w1));
      qB = __hadd2(qB, __hadd2(w2, w3));
      A0 = __hfma2(w0, asH2(h0.x), A0); A1 = __hfma2(w0, asH2(h0.y), A1);
      A2 = __hfma2(w0, asH2(h0.z), A2); A3 = __hfma2(w0, asH2(h0.w), A3);
      B0 = __hfma2(w1, asH2(h1.x), B0); B1 = __hfma2(w1, asH2(h1.y), B1);
      B2 = __hfma2(w1, asH2(h1.z), B2); B3 = __hfma2(w1, asH2(h1.w), B3);
      A0 = __hfma2(w2, asH2(h2.x), A0); A1 = __hfma2(w2, asH2(h2.y), A1);
      A2 = __hfma2(w2, asH2(h2.z), A2); A3 = __hfma2(w2, asH2(h2.w), A3);
      B0 = __hfma2(w3, asH2(h3.x), B0); B1 = __hfma2(w3, asH2(h3.y), B1);
      B2 = __hfma2(w3, asH2(h3.z), B2); B3 = __hfma2(w3, asH2(h3.w), B3);
    }
    for (; i < cnt; ++i) {
      const int2 e = wst[wib][oct][i][headq];
      const uint4 hv = *(const uint4*)(hp + ((size_t)e.x << 6) + 8 * l);
      const __half2 w = asH2(e.y);
      qA = __hadd2(qA, w);
      A0 = __hfma2(w, asH2(hv.x), A0); A1 = __hfma2(w, asH2(hv.y), A1);
      A2 = __hfma2(w, asH2(hv.z), A2); A3 = __hfma2(w, asH2(hv.w), A3);
    }
  }

  const float c0 = __low2float(A0) + __low2float(B0);
  const float c1 = __high2float(A0) + __high2float(B0);
  const float c2 = __low2float(A1) + __low2float(B1);
  const float c3 = __high2float(A1) + __high2float(B1);
  const float c4 = __low2float(A2) + __low2float(B2);
  const float c5 = __high2float(A2) + __high2float(B2);
  const float c6 = __low2float(A3) + __low2float(B3);
  const float c7 = __high2float(A3) + __high2float(B3);
  const float qf = __low2float(qA) + __low2float(qB);

  const float inv = 1.f / fmaxf(qf, 1e-16f);
  const uint4 hr = *(const uint4*)(hp + ((size_t)nc << 6) + 8 * l);
  const float2 r0 = __half22float2(asH2(hr.x));
  const float2 r1 = __half22float2(asH2(hr.y));
  const float2 r2 = __half22float2(asH2(hr.z));
  const float2 r3 = __half22float2(asH2(hr.w));
  const float4 bi0 = *(const float4*)(bias + 8 * l);
  const float4 bi1 = *(const float4*)(bias + 8 * l + 4);
  float v0 = c0 * inv + r0.x + bi0.x;
  float v1 = c1 * inv + r0.y + bi0.y;
  float v2 = c2 * inv + r1.x + bi0.z;
  float v3 = c3 * inv + r1.y + bi0.w;
  float v4 = c4 * inv + r2.x + bi1.x;
  float v5 = c5 * inv + r2.y + bi1.y;
  float v6 = c6 * inv + r3.x + bi1.z;
  float v7 = c7 * inv + r3.y + bi1.w;
  {
    float s = ((v0 + v1) + (v2 + v3)) + ((v4 + v5) + (v6 + v7));
    s += __shfl_xor(s, 1, 64); s += __shfl_xor(s, 2, 64); s += __shfl_xor(s, 4, 64);
    const float mu = s * (1.f / 64.f);
    const float d0 = v0 - mu, d1 = v1 - mu, d2 = v2 - mu, d3 = v3 - mu;
    const float d4 = v4 - mu, d5 = v5 - mu, d6 = v6 - mu, d7 = v7 - mu;
    float vs = ((d0 * d0 + d1 * d1) + (d2 * d2 + d3 * d3)) +
               ((d4 * d4 + d5 * d5) + (d6 * d6 + d7 * d7));
    vs += __shfl_xor(vs, 1, 64); vs += __shfl_xor(vs, 2, 64); vs += __shfl_xor(vs, 4, 64);
    const float rs = rsqrtf(vs * (1.f / 64.f) + 1e-5f);
    const float4 g0 = *(const float4*)(gamma + 8 * l);
    const float4 g1 = *(const float4*)(gamma + 8 * l + 4);
    const float4 e0 = *(const float4*)(beta + 8 * l);
    const float4 e1 = *(const float4*)(beta + 8 * l + 4);
    v0 = fmaxf(d0 * rs * g0.x + e0.x, 0.f);
    v1 = fmaxf(d1 * rs * g0.y + e0.y, 0.f);
    v2 = fmaxf(d2 * rs * g0.z + e0.z, 0.f);
    v3 = fmaxf(d3 * rs * g0.w + e0.w, 0.f);
    v4 = fmaxf(d4 * rs * g1.x + e1.x, 0.f);
    v5 = fmaxf(d5 * rs * g1.y + e1.y, 0.f);
    v6 = fmaxf(d6 * rs * g1.z + e1.z, 0.f);
    v7 = fmaxf(d7 * rs * g1.w + e1.w, 0.f);
  }
  if (valid) {
    const __half2 o0 = __floats2half2_rn(v0, v1);
    const __half2 o1 = __floats2half2_rn(v2, v3);
    const __half2 o2 = __floats2half2_rn(v4, v5);
    const __half2 o3 = __floats2half2_rn(v6, v7);
    uint4 o;
    o.x = *(const unsigned*)&o0; o.y = *(const unsigned*)&o1;
    o.z = *(const unsigned*)&o2; o.w = *(const unsigned*)&o3;
    *(uint4*)(out + (size_t)n * 64 + 8 * l) = o;
  }
}

// ---------------- Edge aggregation, H=1 (32 ch): 16 nodes/wave, 16B/lane ----------------
__global__ __launch_bounds__(256)
void gat_edge1(const __half* __restrict__ hh,
               const float* __restrict__ sa, const float* __restrict__ da,
               const int* __restrict__ rowp, const int* __restrict__ col,
               const float* __restrict__ bias, float* __restrict__ out, int N) {
  __shared__ int2 wst[4][16][5];      // [wave][node(16)][edge(4)+pad]
  const int t = (int)threadIdx.x;
  const int lane = t & 63;
  const int wib = t >> 6;
  const int nq = lane >> 2;           // node within wave
  const int l = lane & 3;             // channels 8l .. 8l+7
  const int wgl = (int)((blockIdx.x * blockDim.x + t) >> 6);
  const int n = wgl * 16 + nq;
  const bool valid = (n < N);
  const int nc = valid ? n : N - 1;
  const int beg = rowp[nc];
  const int end = rowp[nc + 1];
  const float dv = da[nc];
  const __half* __restrict__ hp = hh;

  const __half2 z = __float2half2_rn(0.f);
  __half2 A0 = z, A1 = z, A2 = z, A3 = z;
  __half2 B0 = z, B1 = z, B2 = z, B3 = z;
  __half2 qA = z, qB = z;

  int sP = 0; float pP = 0.f;
  if (beg < end) {
    const int c0 = min(4, end - beg);
    if (l < c0) { sP = col[beg + l]; pP = sa[sP]; }
  }

  for (int b0 = beg; b0 < end; b0 += 4) {
    const int cnt = min(4, end - b0);
    if (l < cnt) {
      int2 e; e.x = sP; e.y = packsplat(__expf(leaky(pP + dv)));
      wst[wib][nq][l] = e;
    }
    const int nb0 = b0 + 4;
    if (nb0 < end) {
      const int ncnt = min(4, end - nb0);
      if (l < ncnt) { sP = col[nb0 + l]; pP = sa[sP]; }
    }
    if (cnt == 4) {
      const int2 e0 = wst[wib][nq][0];
      const int2 e1 = wst[wib][nq][1];
      const int2 e2 = wst[wib][nq][2];
      const int2 e3 = wst[wib][nq][3];
      const uint4 h0 = *(const uint4*)(hp + ((size_t)e0.x << 5) + 8 * l);
      const uint4 h1 = *(const uint4*)(hp + ((size_t)e1.x << 5) + 8 * l);
      const uint4 h2 = *(const uint4*)(hp + ((size_t)e2.x << 5) + 8 * l);
      const uint4 h3 = *(const uint4*)(hp + ((size_t)e3.x << 5) + 8 * l);
      const __half2 w0 = asH2(e0.y), w1 = asH2(e1.y), w2 = asH2(e2.y), w3 = asH2(e3.y);
      qA = __hadd2(qA, __hadd2(w0, w1));
      qB = __hadd2(qB, __hadd2(w2, w3));
      A0 = __hfma2(w0, asH2(h0.x), A0); A1 = __hfma2(w0, asH2(h0.y), A1);
      A2 = __hfma2(w0, asH2(h0.z), A2); A3 = __hfma2(w0, asH2(h0.w), A3);
      B0 = __hfma2(w1, asH2(h1.x), B0); B1 = __hfma2(w1, asH2(h1.y), B1);
      B2 = __hfma2(w1, asH2(h1.z), B2); B3 = __hfma2(w1, asH2(h1.w), B3);
      A0 = __hfma2(w2, asH2(h2.x), A0); A1 = __hfma2(w2, asH2(h2.y), A1);
      A2 = __hfma2(w2, asH2(h2.z), A2); A3 = __hfma2(w2, asH2(h2.w), A3);
      B0 = __hfma2(w3, asH2(h3.x), B0); B1 = __hfma2(w3, asH2(h3.y), B1);
      B2 = __hfma2(w3, asH2(h3.z), B2); B3 = __hfma2(w3, asH2(h3.w), B3);
    } else {
      for (int i = 0; i < cnt; ++i) {
        const int2 e = wst[wib][nq][i];
        const uint4 hv = *(const uint4*)(hp + ((size_t)e.x << 5) + 8 * l);
        const __half2 w = asH2(e.y);
        qA = __hadd2(qA, w);
        A0 = __hfma2(w, asH2(hv.x), A0); A1 = __hfma2(w, asH2(hv.y), A1);
        A2 = __hfma2(w, asH2(hv.z), A2); A3 = __hfma2(w, asH2(hv.w), A3);
      }
    }
  }

  if (valid) {
    const float c0 = __low2float(A0) + __low2float(B0);
    const float c1 = __high2float(A0) + __high2float(B0);
    const float c2 = __low2float(A1) + __low2float(B1);
    const float c3 = __high2float(A1) + __high2float(B1);
    const float c4 = __low2float(A2) + __low2float(B2);
    const float c5 = __high2float(A2) + __high2float(B2);
    const float c6 = __low2float(A3) + __low2float(B3);
    const float c7 = __high2float(A3) + __high2float(B3);
    const float qf = __low2float(qA) + __low2float(qB);
    const float inv = 1.f / fmaxf(qf, 1e-16f);
    const uint4 hr = *(const uint4*)(hp + ((size_t)nc << 5) + 8 * l);
    const float2 r0 = __half22float2(asH2(hr.x));
    const float2 r1 = __half22float2(asH2(hr.y));
    const float2 r2 = __half22float2(asH2(hr.z));
    const float2 r3 = __half22float2(asH2(hr.w));
    const float4 bi0 = *(const float4*)(bias + 8 * l);
    const float4 bi1 = *(const float4*)(bias + 8 * l + 4);
    float4 oA, oB;
    oA.x = c0 * inv + r0.x + bi0.x;
    oA.y = c1 * inv + r0.y + bi0.y;
    oA.z = c2 * inv + r1.x + bi0.z;
    oA.w = c3 * inv + r1.y + bi0.w;
    oB.x = c4 * inv + r2.x + bi1.x;
    oB.y = c5 * inv + r2.y + bi1.y;
    oB.z = c6 * inv + r3.x + bi1.z;
    oB.w = c7 * inv + r3.y + bi1.w;
    *(float4*)(out + (size_t)n * 32 + 8 * l) = oA;
    *(float4*)(out + (size_t)n * 32 + 8 * l + 4) = oB;
  }
}

// ---------------- CSR build: atomic-free radix partition (bucket-major cntmat) ----------------
__global__ __launch_bounds__(256)
void k_hist_chunk(const int* __restrict__ dst, int* __restrict__ cntmat,
                  int E, int NB, int NW) {
  __shared__ int lh[NBMAX];
  const int t = (int)threadIdx.x;
  const int chunk = (int)blockIdx.x;
  const int c0 = chunk * CHUNK;
  const int cnt = min(CHUNK, E - c0);
  for (int b = t; b < NB; b += 256) lh[b] = 0;
  __syncthreads();
  for (int i = t; i < cnt; i += 256)
    atomicAdd(&lh[dst[c0 + i] >> BSH], 1);
  __syncthreads();
  for (int b = t; b < NB; b += 256)
    cntmat[(size_t)b * NW + chunk] = lh[b];
}

template<int VPT>
__global__ __launch_bounds__(256)
void k_colscan(int* __restrict__ cntmat, int* __restrict__ bcnt, int NW) {
  __shared__ int sm[256];
  const int b = (int)blockIdx.x;
  int* row = cntmat + (size_t)b * NW;
  const int t = (int)threadIdx.x;
  int v[VPT];
  int run = 0;
  #pragma unroll
  for (int j = 0; j < VPT; ++j) {
    const int c = t * VPT + j;
    v[j] = (c < NW) ? row[c] : 0;
    run += v[j];
  }
  sm[t] = run;
  __syncthreads();
  #pragma unroll
  for (int off = 1; off < 256; off <<= 1) {
    int xv = (t >= off) ? sm[t - off] : 0;
    __syncthreads();
    sm[t] += xv;
    __syncthreads();
  }
  int excl = sm[t] - run;
  #pragma unroll
  for (int j = 0; j < VPT; ++j) {
    const int c = t * VPT + j;
    if (c < NW) row[c] = excl;
    excl += v[j];
  }
  if (t == 255) bcnt[b] = sm[255];
}

__global__ void k_bscan(const int* __restrict__ bcnt, int nb,
                        int* __restrict__ bstart, int* __restrict__ rowp_last, int E) {
  __shared__ int sm[256];
  const int t = (int)threadIdx.x;
  int v[4];
  #pragma unroll
  for (int j = 0; j < 4; ++j) { int i = t * 4 + j; v[j] = (i < nb) ? bcnt[i] : 0; }
  const int tot = v[0] + v[1] + v[2] + v[3];
  sm[t] = tot; __syncthreads();
  #pragma unroll
  for (int off = 1; off < 256; off <<= 1) {
    int xv = (t >= off) ? sm[t - off] : 0;
    __syncthreads();
    sm[t] += xv;
    __syncthreads();
  }
  int excl = sm[t] - tot;
  #pragma unroll
  for (int j = 0; j < 4; ++j) {
    int i = t * 4 + j;
    if (i < nb) { bstart[i] = excl; excl += v[j]; }
  }
  if (t == 0) { bstart[nb] = E; *rowp_last = E; }
}

__global__ __launch_bounds__(256)
void k_part(const int* __restrict__ src, const int* __restrict__ dst,
            const int* __restrict__ bstart, const int* __restrict__ cntmat,
            int* __restrict__ pairs, int E, int NB, int NW) {
  __shared__ int lh[NBMAX];
  __shared__ int lofs[NBMAX];
  __shared__ int gofs[NBMAX];
  __shared__ int stg[CHUNK];
  __shared__ short stgb[CHUNK];
  __shared__ int bsum[256];
  const int t = (int)threadIdx.x;
  const int chunk = (int)blockIdx.x;
  const int c0 = chunk * CHUNK;
  const int cnt = min(CHUNK, E - c0);

  for (int b = t; b < NB; b += 256) lh[b] = 0;
  __syncthreads();
  for (int i = t; i < cnt; i += 256)
    atomicAdd(&lh[dst[c0 + i] >> BSH], 1);
  __syncthreads();

  int v[4]; int run = 0;
  #pragma unroll
  for (int j = 0; j < 4; ++j) {
    const int b = t * 4 + j;
    v[j] = (b < NB) ? lh[b] : 0;
    run += v[j];
  }
  bsum[t] = run;
  __syncthreads();
  #pragma unroll
  for (int off = 1; off < 256; off <<= 1) {
    int xv = (t >= off) ? bsum[t - off] : 0;
    __syncthreads();
    bsum[t] += xv;
    __syncthreads();
  }
  int base = bsum[t] - run;
  #pragma unroll
  for (int j = 0; j < 4; ++j) {
    const int b = t * 4 + j;
    if (b < NB) lofs[b] = base;
    base += v[j];
  }
  __syncthreads();

  for (int b = t; b < NB; b += 256) {
    gofs[b] = bstart[b] + cntmat[(size_t)b * NW + chunk];
    lh[b] = lofs[b];
  }
  __syncthreads();

  for (int i = t; i < cnt; i += 256) {
    const int d = dst[c0 + i];
    const int b = d >> BSH;
    const int p = atomicAdd(&lh[b], 1);   // LDS only
    stg[p] = (src[c0 + i] << BSH) | (d & (BN - 1));
    stgb[p] = (short)b;
  }
  __syncthreads();

  for (int i = t; i < cnt; i += 256) {
    const int b = (int)stgb[i];
    pairs[gofs[b] + (i - lofs[b])] = stg[i];
  }
}

__global__ __launch_bounds__(256)
void k_bucket_csr(const int* __restrict__ pairs, const int* __restrict__ bstart,
                  int* __restrict__ rowp, int* __restrict__ col, int N) {
  __shared__ int ldeg[BN];
  __shared__ int lofs[BN];
  const int b = (int)blockIdx.x;
  const int t = (int)threadIdx.x;
  const int base = b << BSH;
  const int nn = min(BN, N - base);
  const int s0 = bstart[b];
  const int s1 = bstart[b + 1];

  if (t < BN) ldeg[t] = 0;
  __syncthreads();
  for (int i = s0 + t; i < s1; i += 256)
    atomicAdd(&ldeg[pairs[i] & (BN - 1)], 1);
  __syncthreads();
  if (t < BN) lofs[t] = ldeg[t];
  __syncthreads();
  #pragma unroll
  for (int off = 1; off < BN; off <<= 1) {
    int v = (t < BN && t >= off) ? lofs[t - off] : 0;
    __syncthreads();
    if (t < BN) lofs[t] += v;
    __syncthreads();
  }
  if (t < BN) {
    const int ofs = s0 + lofs[t] - ldeg[t];
    if (t < nn) rowp[base + t] = ofs;
    ldeg[t] = ofs;
  }
  __syncthreads();
  for (int i = s0 + t; i < s1; i += 256) {
    const int pr = pairs[i];
    const int p = atomicAdd(&ldeg[pr & (BN - 1)], 1);
    col[p] = pr >> BSH;
  }
}

extern "C" void kernel_launch(void* const* d_in, const int* in_sizes, int n_in,
                              void* d_out, int out_size, void* d_ws, size_t ws_size,
                              hipStream_t stream) {
  const float* x   = (const float*)d_in[0];
  const int* esrc  = (const int*)d_in[1];
  const int* edst  = (const int*)d_in[2];
  const float* W1  = (const float*)d_in[3];
  const float* as1 = (const float*)d_in[4];
  const float* ad1 = (const float*)d_in[5];
  const float* b1  = (const float*)d_in[6];
  const float* W2  = (const float*)d_in[7];
  const float* as2 = (const float*)d_in[8];
  const float* ad2 = (const float*)d_in[9];
  const float* b2  = (const float*)d_in[10];
  const float* W3  = (const float*)d_in[11];
  const float* as3 = (const float*)d_in[12];
  const float* ad3 = (const float*)d_in[13];
  const float* b3  = (const float*)d_in[14];
  const float* g1  = (const float*)d_in[15];
  const float* be1 = (const float*)d_in[16];
  const float* g2  = (const float*)d_in[17];
  const float* be2 = (const float*)d_in[18];

  const int N = in_sizes[0] / 128;
  const int E = in_sizes[1];
  const int NB = (N + BN - 1) / BN;
  const int NW = (E + CHUNK - 1) / CHUNK;

  char* ws = (char*)d_ws;
  size_t off = 0;
  auto alloc = [&](size_t bytes) -> void* {
    void* p = ws + off;
    off = (off + bytes + 255) & ~(size_t)255;
    return p;
  };
  __half* lnbuf = (__half*)alloc((size_t)N * 64 * 2);
  __half* hh   = (__half*)alloc((size_t)N * 64 * 2);
  float* sab   = (float*)alloc((size_t)N * 2 * 4);
  float* dab   = (float*)alloc((size_t)N * 2 * 4);
  int* rowp    = (int*)alloc((size_t)(N + 1) * 4);
  int* colb    = (int*)alloc((size_t)E * 4);
  int* bcnt    = (int*)alloc((size_t)NB * 4);
  int* bstart  = (int*)alloc((size_t)(NB + 1) * 4);
  int* cntmat  = (int*)alloc((size_t)NB * NW * 4);
  // pairs buffer: reuse d_out (N*32 floats = 12.8MB >= E*4 = 6.4MB);
  // lifetime ends before the final layer writes d_out.
  int* pairs = (E <= out_size) ? (int*)d_out : (int*)alloc((size_t)E * 4);
  (void)ws_size; (void)n_in;

  // ---- CSR build (zero global atomics) ----
  k_hist_chunk<<<NW, 256, 0, stream>>>(edst, cntmat, E, NB, NW);
  if (NW <= 512)        k_colscan<2><<<NB, 256, 0, stream>>>(cntmat, bcnt, NW);
  else if (NW <= 1024)  k_colscan<4><<<NB, 256, 0, stream>>>(cntmat, bcnt, NW);
  else                  k_colscan<8><<<NB, 256, 0, stream>>>(cntmat, bcnt, NW);
  k_bscan<<<1, 256, 0, stream>>>(bcnt, NB, bstart, rowp + N, E);
  k_part<<<NW, 256, 0, stream>>>(esrc, edst, bstart, cntmat, pairs, E, NB, NW);
  k_bucket_csr<<<NB, 256, 0, stream>>>(pairs, bstart, rowp, colb, N);

  const int gG  = (N + 63) / 64;     // 64 nodes per block (all layers)
  const int gE2 = (N + 31) / 32;     // 8 nodes/wave * 4 waves/block
  const int gE1 = (N + 63) / 64;     // 16 nodes/wave * 4 waves/block

  // ---- Layer 1: 128 -> (2x32) + LN + ReLU ----
  gat_gemm5<128, 64, 2, true><<<gG, 256, 0, stream>>>(x, W1, as1, ad1, hh, sab, dab, N);
  gat_edge2<<<gE2, 256, 0, stream>>>(hh, sab, dab, rowp, colb, b1, g1, be1, lnbuf, N);

  // ---- Layer 2: 64 -> (2x32) + LN + ReLU ----
  gat_gemm5<64, 64, 2, false><<<gG, 256, 0, stream>>>(lnbuf, W2, as2, ad2, hh, sab, dab, N);
  gat_edge2<<<gE2, 256, 0, stream>>>(hh, sab, dab, rowp, colb, b2, g2, be2, lnbuf, N);

  // ---- Layer 3: 64 -> (1x32), no LN ----
  gat_gemm5<64, 32, 1, false><<<gG, 256, 0, stream>>>(lnbuf, W3, as3, ad3, hh, sab, dab, N);
  gat_edge1<<<gE1, 256, 0, stream>>>(hh, sab, dab, rowp, colb, b3, (float*)d_out, N);
}